// Round 1
// baseline (1030.678 us; speedup 1.0000x reference)
//
#include <hip/hip_runtime.h>
#include <hip/hip_bf16.h>
#include <math.h>

#define N_NODES 100000
#define E_EDGES 3200000
#define F_INF   256
#define HIDF    128
#define C_OUT   40

// ---------------------------------------------------------------------------
// CSR build: histogram of dst, exclusive scan, bucket fill with (src, weight)
// ---------------------------------------------------------------------------

__global__ void hist_kernel(const int* __restrict__ ei, int* __restrict__ deg) {
    int idx = blockIdx.x * blockDim.x + threadIdx.x;
    int stride = gridDim.x * blockDim.x;
    for (int e = idx; e < E_EDGES; e += stride)
        atomicAdd(&deg[ei[E_EDGES + e]], 1);
}

// single-block scan: 1024 threads x 4 elems = 4096/chunk, 25 chunks
__global__ void scan_kernel(const int* __restrict__ deg, int* __restrict__ rowptr) {
    __shared__ int warpsums[16];
    __shared__ int s_carry;
    int tid = threadIdx.x, lane = tid & 63, wid = tid >> 6;
    if (tid == 0) { s_carry = 0; rowptr[0] = 0; }
    __syncthreads();
    for (int base = 0; base < N_NODES; base += 4096) {
        int i0 = base + tid * 4;
        int v[4];
        #pragma unroll
        for (int j = 0; j < 4; ++j) {
            int i = i0 + j;
            v[j] = (i < N_NODES) ? deg[i] : 0;
        }
        int tsum = v[0] + v[1] + v[2] + v[3];
        int sc = tsum;  // inclusive wave scan
        #pragma unroll
        for (int off = 1; off < 64; off <<= 1) {
            int t = __shfl_up(sc, off);
            if (lane >= off) sc += t;
        }
        if (lane == 63) warpsums[wid] = sc;
        __syncthreads();
        if (tid == 0) {
            int run = 0;
            #pragma unroll
            for (int w = 0; w < 16; ++w) { run += warpsums[w]; warpsums[w] = run; }
        }
        __syncthreads();
        int wbase = (wid > 0) ? warpsums[wid - 1] : 0;
        int carry = s_carry;
        int run = carry + wbase + (sc - tsum);  // exclusive prefix for first elem
        #pragma unroll
        for (int j = 0; j < 4; ++j) {
            int i = i0 + j;
            run += v[j];
            if (i < N_NODES) rowptr[i + 1] = run;
        }
        __syncthreads();
        if (tid == 0) s_carry = carry + warpsums[15];
        __syncthreads();
    }
}

__global__ void fill_kernel(const int* __restrict__ ei, const float* __restrict__ ew,
                            const int* __restrict__ rowptr, int* __restrict__ cursor,
                            int2* __restrict__ srcw) {
    int idx = blockIdx.x * blockDim.x + threadIdx.x;
    int stride = gridDim.x * blockDim.x;
    for (int e = idx; e < E_EDGES; e += stride) {
        int dst = ei[E_EDGES + e];
        int pos = atomicAdd(&cursor[dst], 1);
        srcw[rowptr[dst] + pos] = make_int2(ei[e], __float_as_int(ew[e]));
    }
}

// ---------------------------------------------------------------------------
// GEMM1: h[100000,128] = x[100000,256] @ W1[256,128]   (f32 vector FMA)
// tile 64x128, BK=32, 256 thr, per-thread 8x4 acc. LDS xT stride 68.
// ---------------------------------------------------------------------------
__global__ __launch_bounds__(256) void gemm1_kernel(const float* __restrict__ x,
                                                    const float* __restrict__ W1,
                                                    float* __restrict__ h) {
    __shared__ float xT[32 * 68];   // [k][row], stride 68 (16B aligned, conflict-lite)
    __shared__ float wt[32 * 128];  // [k][c]
    int tid = threadIdx.x;
    int tx = tid & 31, ty = tid >> 5;
    int m0 = blockIdx.x * 64;
    float acc[8][4] = {};
    for (int kb = 0; kb < 256; kb += 32) {
        #pragma unroll
        for (int t = 0; t < 2; ++t) {            // stage x -> xT (transposed)
            int i = tid + t * 256;               // float4 id, 0..511
            int row = i >> 3, kc4 = i & 7;
            int gr = m0 + row; if (gr > N_NODES - 1) gr = N_NODES - 1;
            float4 g = *(const float4*)&x[(size_t)gr * F_INF + kb + kc4 * 4];
            int k = kc4 * 4;
            xT[(k + 0) * 68 + row] = g.x;
            xT[(k + 1) * 68 + row] = g.y;
            xT[(k + 2) * 68 + row] = g.z;
            xT[(k + 3) * 68 + row] = g.w;
        }
        #pragma unroll
        for (int t = 0; t < 4; ++t) {            // stage W1 tile
            int i = tid + t * 256;               // float4 id, 0..1023
            int k = i >> 5, c4 = i & 31;
            *(float4*)&wt[k * 128 + c4 * 4] =
                *(const float4*)&W1[(size_t)(kb + k) * 128 + c4 * 4];
        }
        __syncthreads();
        #pragma unroll
        for (int k = 0; k < 32; ++k) {
            float4 wv = *(float4*)&wt[k * 128 + tx * 4];
            float4 xa = *(float4*)&xT[k * 68 + ty * 8];
            float4 xb = *(float4*)&xT[k * 68 + ty * 8 + 4];
            float xr[8] = {xa.x, xa.y, xa.z, xa.w, xb.x, xb.y, xb.z, xb.w};
            #pragma unroll
            for (int i = 0; i < 8; ++i) {
                acc[i][0] += xr[i] * wv.x;
                acc[i][1] += xr[i] * wv.y;
                acc[i][2] += xr[i] * wv.z;
                acc[i][3] += xr[i] * wv.w;
            }
        }
        __syncthreads();
    }
    #pragma unroll
    for (int i = 0; i < 8; ++i) {
        int r = m0 + ty * 8 + i;
        if (r < N_NODES) {
            float4 o = {acc[i][0], acc[i][1], acc[i][2], acc[i][3]};
            *(float4*)&h[(size_t)r * HIDF + tx * 4] = o;
        }
    }
}

// ---------------------------------------------------------------------------
// agg1: per-node wave gather-accumulate over CSR, fused +b1 and relu
// lane holds 2 features (float2): 64 lanes x 8B = 512B coalesced per edge
// ---------------------------------------------------------------------------
__global__ __launch_bounds__(256) void agg1_kernel(const float* __restrict__ h,
                                                   const int2* __restrict__ srcw,
                                                   const int* __restrict__ rowptr,
                                                   const float* __restrict__ b1,
                                                   float* __restrict__ hact) {
    int lane = threadIdx.x & 63;
    int node = blockIdx.x * 4 + (threadIdx.x >> 6);
    if (node >= N_NODES) return;
    int beg = rowptr[node], end = rowptr[node + 1];
    float2 acc = {0.f, 0.f};
    const float2* hp = (const float2*)h;
    for (int base = beg; base < end; base += 64) {
        int idx = base + lane;
        int2 sw = srcw[idx < end ? idx : end - 1];
        int cnt = end - base; if (cnt > 64) cnt = 64;
        #pragma unroll 4
        for (int j = 0; j < cnt; ++j) {
            int s = __shfl(sw.x, j);
            float w = __int_as_float(__shfl(sw.y, j));
            float2 hv = hp[(size_t)s * 64 + lane];
            acc.x += w * hv.x;
            acc.y += w * hv.y;
        }
    }
    float2 bb = ((const float2*)b1)[lane];
    float2 o;
    o.x = fmaxf(acc.x + bb.x, 0.f);
    o.y = fmaxf(acc.y + bb.y, 0.f);
    ((float2*)hact)[(size_t)node * 64 + lane] = o;
}

// ---------------------------------------------------------------------------
// GEMM2: h2[100000,40] = hact[100000,128] @ W2[128,40]
// 320 thr (5 waves), 64 rows/block, full K staged, per-thread 8 rows x 1 col
// ---------------------------------------------------------------------------
__global__ __launch_bounds__(320) void gemm2_kernel(const float* __restrict__ hact,
                                                    const float* __restrict__ W2,
                                                    float* __restrict__ h2) {
    __shared__ float xT[128 * 68];   // [k][row]
    __shared__ float w2[128 * 40];
    int tid = threadIdx.x;
    int tx = tid % 40, ty = tid / 40;   // tx: col 0..39, ty: row-group 0..7
    int m0 = blockIdx.x * 64;
    for (int i = tid; i < 128 * 40; i += 320) w2[i] = W2[i];
    for (int i = tid; i < 2048; i += 320) {       // 64 rows x 32 float4
        int row = i >> 5, kc4 = i & 31;
        int gr = m0 + row; if (gr > N_NODES - 1) gr = N_NODES - 1;
        float4 g = *(const float4*)&hact[(size_t)gr * HIDF + kc4 * 4];
        int k = kc4 * 4;
        xT[(k + 0) * 68 + row] = g.x;
        xT[(k + 1) * 68 + row] = g.y;
        xT[(k + 2) * 68 + row] = g.z;
        xT[(k + 3) * 68 + row] = g.w;
    }
    __syncthreads();
    float acc[8] = {};
    #pragma unroll 4
    for (int k = 0; k < 128; ++k) {
        float wv = w2[k * 40 + tx];
        float4 xa = *(float4*)&xT[k * 68 + ty * 8];
        float4 xb = *(float4*)&xT[k * 68 + ty * 8 + 4];
        acc[0] += xa.x * wv; acc[1] += xa.y * wv;
        acc[2] += xa.z * wv; acc[3] += xa.w * wv;
        acc[4] += xb.x * wv; acc[5] += xb.y * wv;
        acc[6] += xb.z * wv; acc[7] += xb.w * wv;
    }
    #pragma unroll
    for (int i = 0; i < 8; ++i) {
        int r = m0 + ty * 8 + i;
        if (r < N_NODES) h2[(size_t)r * C_OUT + tx] = acc[i];
    }
}

// ---------------------------------------------------------------------------
// agg2: per-node wave gather over CSR, fused +b2 and log_softmax (40 classes)
// ---------------------------------------------------------------------------
__global__ __launch_bounds__(256) void agg2_kernel(const float* __restrict__ h2,
                                                   const int2* __restrict__ srcw,
                                                   const int* __restrict__ rowptr,
                                                   const float* __restrict__ b2,
                                                   float* __restrict__ out) {
    int lane = threadIdx.x & 63;
    int node = blockIdx.x * 4 + (threadIdx.x >> 6);
    if (node >= N_NODES) return;
    int beg = rowptr[node], end = rowptr[node + 1];
    float acc = 0.f;
    for (int base = beg; base < end; base += 64) {
        int idx = base + lane;
        int2 sw = srcw[idx < end ? idx : end - 1];
        int cnt = end - base; if (cnt > 64) cnt = 64;
        #pragma unroll 4
        for (int j = 0; j < cnt; ++j) {
            int s = __shfl(sw.x, j);
            float w = __int_as_float(__shfl(sw.y, j));
            if (lane < C_OUT) acc += w * h2[(size_t)s * C_OUT + lane];
        }
    }
    float v = (lane < C_OUT) ? acc + b2[lane] : -INFINITY;
    float m = v;
    #pragma unroll
    for (int off = 32; off; off >>= 1) m = fmaxf(m, __shfl_xor(m, off));
    float ex = (lane < C_OUT) ? expf(v - m) : 0.f;
    float ssum = ex;
    #pragma unroll
    for (int off = 32; off; off >>= 1) ssum += __shfl_xor(ssum, off);
    float r = v - m - logf(ssum);
    if (lane < C_OUT) out[(size_t)node * C_OUT + lane] = r;
}

// ---------------------------------------------------------------------------

extern "C" void kernel_launch(void* const* d_in, const int* in_sizes, int n_in,
                              void* d_out, int out_size, void* d_ws, size_t ws_size,
                              hipStream_t stream) {
    const float* x  = (const float*)d_in[0];
    const int*   ei = (const int*)d_in[1];      // [2,E]: row0=src, row1=dst
    const float* ew = (const float*)d_in[2];
    const float* W1 = (const float*)d_in[3];
    const float* b1 = (const float*)d_in[4];
    const float* W2 = (const float*)d_in[5];
    const float* b2 = (const float*)d_in[6];
    float* out = (float*)d_out;

    char* ws = (char*)d_ws;
    size_t off = 0;
    auto alloc = [&](size_t bytes) -> void* {
        void* p = ws + off;
        off += (bytes + 255) & ~(size_t)255;
        return p;
    };
    float* h      = (float*)alloc((size_t)N_NODES * HIDF * 4);   // 51.2 MB
    float* hact   = (float*)alloc((size_t)N_NODES * HIDF * 4);   // 51.2 MB
    float* h2     = (float*)alloc((size_t)N_NODES * C_OUT * 4);  // 16 MB
    int*   rowptr = (int*)alloc((size_t)(N_NODES + 1) * 4);
    int*   deg    = (int*)alloc((size_t)N_NODES * 4);
    int*   cursor = (int*)alloc((size_t)N_NODES * 4);
    int2*  srcw   = (int2*)alloc((size_t)E_EDGES * 8);           // 25.6 MB
    // total ~145.6 MB of d_ws

    hipMemsetAsync(deg, 0, (size_t)N_NODES * 4, stream);
    hipMemsetAsync(cursor, 0, (size_t)N_NODES * 4, stream);

    hist_kernel<<<4096, 256, 0, stream>>>(ei, deg);
    scan_kernel<<<1, 1024, 0, stream>>>(deg, rowptr);
    fill_kernel<<<4096, 256, 0, stream>>>(ei, ew, rowptr, cursor, srcw);

    gemm1_kernel<<<(N_NODES + 63) / 64, 256, 0, stream>>>(x, W1, h);
    agg1_kernel<<<(N_NODES + 3) / 4, 256, 0, stream>>>(h, srcw, rowptr, b1, hact);
    gemm2_kernel<<<(N_NODES + 63) / 64, 320, 0, stream>>>(hact, W2, h2);
    agg2_kernel<<<(N_NODES + 3) / 4, 256, 0, stream>>>(h2, srcw, rowptr, b2, out);
}

// Round 2
// 830.405 us; speedup vs baseline: 1.2412x; 1.2412x over previous
//
#include <hip/hip_runtime.h>
#include <hip/hip_bf16.h>
#include <hip/hip_fp16.h>
#include <math.h>

#define N_NODES 100000
#define E_EDGES 3200000
#define F_INF   256
#define HIDF    128
#define C_OUT   40

typedef __attribute__((ext_vector_type(8))) short bf16x8;
typedef __attribute__((ext_vector_type(4))) float f32x4;

static __device__ __forceinline__ short bf16c(float f) {
    __hip_bfloat16 b = __float2bfloat16(f);
    return *reinterpret_cast<short*>(&b);
}

// ---------------------------------------------------------------------------
// CSR build: histogram of dst, exclusive scan, bucket fill with (src, weight)
// ---------------------------------------------------------------------------

__global__ void hist_kernel(const int* __restrict__ ei, int* __restrict__ deg) {
    int idx = blockIdx.x * blockDim.x + threadIdx.x;
    int stride = gridDim.x * blockDim.x;
    for (int e = idx; e < E_EDGES; e += stride)
        atomicAdd(&deg[ei[E_EDGES + e]], 1);
}

__global__ void scan_kernel(const int* __restrict__ deg, int* __restrict__ rowptr) {
    __shared__ int warpsums[16];
    __shared__ int s_carry;
    int tid = threadIdx.x, lane = tid & 63, wid = tid >> 6;
    if (tid == 0) { s_carry = 0; rowptr[0] = 0; }
    __syncthreads();
    for (int base = 0; base < N_NODES; base += 4096) {
        int i0 = base + tid * 4;
        int v[4];
        #pragma unroll
        for (int j = 0; j < 4; ++j) {
            int i = i0 + j;
            v[j] = (i < N_NODES) ? deg[i] : 0;
        }
        int tsum = v[0] + v[1] + v[2] + v[3];
        int sc = tsum;  // inclusive wave scan
        #pragma unroll
        for (int off = 1; off < 64; off <<= 1) {
            int t = __shfl_up(sc, off);
            if (lane >= off) sc += t;
        }
        if (lane == 63) warpsums[wid] = sc;
        __syncthreads();
        if (tid == 0) {
            int run = 0;
            #pragma unroll
            for (int w = 0; w < 16; ++w) { run += warpsums[w]; warpsums[w] = run; }
        }
        __syncthreads();
        int wbase = (wid > 0) ? warpsums[wid - 1] : 0;
        int carry = s_carry;
        int run = carry + wbase + (sc - tsum);
        #pragma unroll
        for (int j = 0; j < 4; ++j) {
            int i = i0 + j;
            run += v[j];
            if (i < N_NODES) rowptr[i + 1] = run;
        }
        __syncthreads();
        if (tid == 0) s_carry = carry + warpsums[15];
        __syncthreads();
    }
}

__global__ void fill_kernel(const int* __restrict__ ei, const float* __restrict__ ew,
                            const int* __restrict__ rowptr, int* __restrict__ cursor,
                            int2* __restrict__ srcw) {
    int idx = blockIdx.x * blockDim.x + threadIdx.x;
    int stride = gridDim.x * blockDim.x;
    for (int e = idx; e < E_EDGES; e += stride) {
        int dst = ei[E_EDGES + e];
        int pos = atomicAdd(&cursor[dst], 1);
        srcw[rowptr[dst] + pos] = make_int2(ei[e], __float_as_int(ew[e]));
    }
}

// ---------------------------------------------------------------------------
// W1T precompute: W1[256,128] f32 -> W1T[128,256] bf16 (stays L2-resident)
// ---------------------------------------------------------------------------
__global__ void w1t_kernel(const float* __restrict__ W1, short* __restrict__ w1t) {
    int idx = blockIdx.x * 256 + threadIdx.x;  // 0..32767
    int k = idx >> 7, c = idx & 127;
    w1t[c * 256 + k] = bf16c(W1[idx]);
}

// ---------------------------------------------------------------------------
// GEMM1 (MFMA bf16): h[100000,128]fp16 = x[100000,256] @ W1
// 128x128 tile, 4 waves (2x2), BK=64, A in swizzled LDS, B direct from L2.
// ---------------------------------------------------------------------------
__global__ __launch_bounds__(256) void gemm1_kernel(const float* __restrict__ x,
                                                    const short* __restrict__ w1t,
                                                    __half* __restrict__ h) {
    __shared__ short aT[128 * 64];  // [row][k] bf16, XOR-swizzled, 16 KB
    int tid = threadIdx.x;
    int lane = tid & 63, wid = tid >> 6;
    int wr = wid >> 1, wc = wid & 1;
    int m0 = blockIdx.x * 128;
    f32x4 acc[4][4] = {{{0.f}}};
    for (int kb = 0; kb < 256; kb += 64) {
        #pragma unroll
        for (int t = 0; t < 8; ++t) {              // stage A tile, cvt f32->bf16
            int id = tid + t * 256;                // 0..2047: row(128) x chunk4(16)
            int row = id >> 4, c4 = id & 15;
            int gr = m0 + row; if (gr >= N_NODES) gr = N_NODES - 1;
            float4 g = *(const float4*)&x[(size_t)gr * F_INF + kb + c4 * 4];
            short4 s4 = { bf16c(g.x), bf16c(g.y), bf16c(g.z), bf16c(g.w) };
            int byte = row * 128 + c4 * 8;
            byte ^= (row & 7) << 4;
            *(short4*)((char*)aT + byte) = s4;
        }
        __syncthreads();
        #pragma unroll
        for (int km = 0; km < 2; ++km) {
            bf16x8 af[4], bfr[4];
            #pragma unroll
            for (int mi = 0; mi < 4; ++mi) {
                int row = wr * 64 + mi * 16 + (lane & 15);
                int kk = km * 32 + (lane >> 4) * 8;
                int byte = row * 128 + kk * 2;
                byte ^= (row & 7) << 4;
                af[mi] = *(bf16x8*)((char*)aT + byte);
            }
            #pragma unroll
            for (int ni = 0; ni < 4; ++ni) {
                int col = wc * 64 + ni * 16 + (lane & 15);
                int kk = kb + km * 32 + (lane >> 4) * 8;
                bfr[ni] = *(const bf16x8*)&w1t[col * 256 + kk];
            }
            #pragma unroll
            for (int mi = 0; mi < 4; ++mi)
                #pragma unroll
                for (int ni = 0; ni < 4; ++ni)
                    acc[mi][ni] = __builtin_amdgcn_mfma_f32_16x16x32_bf16(
                        af[mi], bfr[ni], acc[mi][ni], 0, 0, 0);
        }
        __syncthreads();
    }
    // C/D: col = lane&15, row = (lane>>4)*4 + r
    #pragma unroll
    for (int mi = 0; mi < 4; ++mi) {
        int rbase = m0 + wr * 64 + mi * 16 + ((lane >> 4) << 2);
        #pragma unroll
        for (int ni = 0; ni < 4; ++ni) {
            int col = wc * 64 + ni * 16 + (lane & 15);
            #pragma unroll
            for (int r = 0; r < 4; ++r) {
                int row = rbase + r;
                if (row < N_NODES)
                    h[(size_t)row * HIDF + col] = __float2half(acc[mi][ni][r]);
            }
        }
    }
}

// ---------------------------------------------------------------------------
// agg1: per-node wave CSR gather, 2 edges/iter (lane = eo*32+fo), fp16 h,
// fused +b1 + relu, fp16 hact out.
// ---------------------------------------------------------------------------
__global__ __launch_bounds__(256) void agg1_kernel(const __half* __restrict__ h,
                                                   const int2* __restrict__ srcw,
                                                   const int* __restrict__ rowptr,
                                                   const float* __restrict__ b1,
                                                   __half* __restrict__ hact) {
    int lane = threadIdx.x & 63;
    int node = blockIdx.x * 4 + (threadIdx.x >> 6);
    if (node >= N_NODES) return;
    int beg = rowptr[node], end = rowptr[node + 1];
    int eo = lane >> 5, fo = lane & 31;          // edge-offset, feature quad
    float4 acc = {0.f, 0.f, 0.f, 0.f};
    const uint2* hp = (const uint2*)h;           // row = 32 x uint2 (4 halfs)
    for (int base = beg; base < end; base += 64) {
        int idx = base + lane;
        int2 sw = srcw[idx < end ? idx : end - 1];
        int cnt = end - base; if (cnt > 64) cnt = 64;
        for (int j = 0; j < cnt; j += 2) {
            int jj = j + eo;
            int s = __shfl(sw.x, jj);
            float w = __int_as_float(__shfl(sw.y, jj));
            if (jj >= cnt) w = 0.f;
            uint2 hv = hp[(size_t)s * 32 + fo];
            float2 f01 = __half22float2(*(__half2*)&hv.x);
            float2 f23 = __half22float2(*(__half2*)&hv.y);
            acc.x += w * f01.x; acc.y += w * f01.y;
            acc.z += w * f23.x; acc.w += w * f23.y;
        }
    }
    acc.x += __shfl_xor(acc.x, 32);
    acc.y += __shfl_xor(acc.y, 32);
    acc.z += __shfl_xor(acc.z, 32);
    acc.w += __shfl_xor(acc.w, 32);
    if (lane < 32) {
        float4 bb = ((const float4*)b1)[fo];
        __half2 o01 = __floats2half2_rn(fmaxf(acc.x + bb.x, 0.f),
                                        fmaxf(acc.y + bb.y, 0.f));
        __half2 o23 = __floats2half2_rn(fmaxf(acc.z + bb.z, 0.f),
                                        fmaxf(acc.w + bb.w, 0.f));
        uint2 ov = { *(uint*)&o01, *(uint*)&o23 };
        ((uint2*)hact)[(size_t)node * 32 + fo] = ov;
    }
}

// ---------------------------------------------------------------------------
// GEMM2: h2[100000,40]fp16 = hact[100000,128]fp16 @ W2[128,40]
// 320 thr (5 waves), 64 rows/block, full K staged, per-thread 8 rows x 1 col
// ---------------------------------------------------------------------------
__global__ __launch_bounds__(320) void gemm2_kernel(const __half* __restrict__ hact,
                                                    const float* __restrict__ W2,
                                                    __half* __restrict__ h2) {
    __shared__ float xT[128 * 68];   // [k][row]
    __shared__ float w2[128 * 40];
    int tid = threadIdx.x;
    int tx = tid % 40, ty = tid / 40;
    int m0 = blockIdx.x * 64;
    for (int i = tid; i < 128 * 40; i += 320) w2[i] = W2[i];
    for (int i = tid; i < 1024; i += 320) {       // 64 rows x 16 chunks(8 halfs)
        int row = i >> 4, c8 = i & 15;
        int gr = m0 + row; if (gr >= N_NODES) gr = N_NODES - 1;
        uint4 v = *(const uint4*)&hact[(size_t)gr * HIDF + c8 * 8];
        const __half2* ph = (const __half2*)&v;
        #pragma unroll
        for (int t = 0; t < 4; ++t) {
            float2 f = __half22float2(ph[t]);
            int k = c8 * 8 + t * 2;
            xT[(k + 0) * 68 + row] = f.x;
            xT[(k + 1) * 68 + row] = f.y;
        }
    }
    __syncthreads();
    float acc[8] = {};
    #pragma unroll 4
    for (int k = 0; k < 128; ++k) {
        float wv = w2[k * 40 + tx];
        float4 xa = *(float4*)&xT[k * 68 + ty * 8];
        float4 xb = *(float4*)&xT[k * 68 + ty * 8 + 4];
        acc[0] += xa.x * wv; acc[1] += xa.y * wv;
        acc[2] += xa.z * wv; acc[3] += xa.w * wv;
        acc[4] += xb.x * wv; acc[5] += xb.y * wv;
        acc[6] += xb.z * wv; acc[7] += xb.w * wv;
    }
    #pragma unroll
    for (int i = 0; i < 8; ++i) {
        int r = m0 + ty * 8 + i;
        if (r < N_NODES) h2[(size_t)r * C_OUT + tx] = __float2half(acc[i]);
    }
}

// ---------------------------------------------------------------------------
// agg2: per-node wave CSR gather (2 edges/iter), fp16 h2, fused +b2 +
// log_softmax (40 classes), f32 out.
// ---------------------------------------------------------------------------
__global__ __launch_bounds__(256) void agg2_kernel(const __half* __restrict__ h2,
                                                   const int2* __restrict__ srcw,
                                                   const int* __restrict__ rowptr,
                                                   const float* __restrict__ b2,
                                                   float* __restrict__ out) {
    int lane = threadIdx.x & 63;
    int node = blockIdx.x * 4 + (threadIdx.x >> 6);
    if (node >= N_NODES) return;
    int beg = rowptr[node], end = rowptr[node + 1];
    int eo = lane >> 5, co = lane & 31;          // co: class pair 0..19 valid
    float2 acc = {0.f, 0.f};
    const uint* h2p = (const uint*)h2;           // row = 20 x uint (half2)
    for (int base = beg; base < end; base += 64) {
        int idx = base + lane;
        int2 sw = srcw[idx < end ? idx : end - 1];
        int cnt = end - base; if (cnt > 64) cnt = 64;
        for (int j = 0; j < cnt; j += 2) {
            int jj = j + eo;
            int s = __shfl(sw.x, jj);
            float w = __int_as_float(__shfl(sw.y, jj));
            if (jj >= cnt) w = 0.f;
            if (co < 20) {
                uint hv = h2p[(size_t)s * 20 + co];
                float2 f = __half22float2(*(__half2*)&hv);
                acc.x += w * f.x; acc.y += w * f.y;
            }
        }
    }
    acc.x += __shfl_xor(acc.x, 32);
    acc.y += __shfl_xor(acc.y, 32);
    float v0 = -INFINITY, v1 = -INFINITY;
    if (co < 20) {
        v0 = acc.x + b2[co * 2];
        v1 = acc.y + b2[co * 2 + 1];
    }
    float m = fmaxf(v0, v1);
    #pragma unroll
    for (int off = 32; off; off >>= 1) m = fmaxf(m, __shfl_xor(m, off));
    float ex = (co < 20 && eo == 0) ? (expf(v0 - m) + expf(v1 - m)) : 0.f;
    #pragma unroll
    for (int off = 32; off; off >>= 1) ex += __shfl_xor(ex, off);
    float ls = logf(ex);
    if (co < 20 && eo == 0) {
        float2 o = { v0 - m - ls, v1 - m - ls };
        ((float2*)out)[(size_t)node * 20 + co] = o;
    }
}

// ---------------------------------------------------------------------------

extern "C" void kernel_launch(void* const* d_in, const int* in_sizes, int n_in,
                              void* d_out, int out_size, void* d_ws, size_t ws_size,
                              hipStream_t stream) {
    const float* x  = (const float*)d_in[0];
    const int*   ei = (const int*)d_in[1];      // [2,E]: row0=src, row1=dst
    const float* ew = (const float*)d_in[2];
    const float* W1 = (const float*)d_in[3];
    const float* b1 = (const float*)d_in[4];
    const float* W2 = (const float*)d_in[5];
    const float* b2 = (const float*)d_in[6];
    float* out = (float*)d_out;

    char* ws = (char*)d_ws;
    size_t off = 0;
    auto alloc = [&](size_t bytes) -> void* {
        void* p = ws + off;
        off += (bytes + 255) & ~(size_t)255;
        return p;
    };
    __half* h      = (__half*)alloc((size_t)N_NODES * HIDF * 2);   // 25.6 MB
    __half* hact   = (__half*)alloc((size_t)N_NODES * HIDF * 2);   // 25.6 MB
    __half* h2     = (__half*)alloc((size_t)N_NODES * C_OUT * 2);  // 8 MB
    short*  w1t    = (short*)alloc((size_t)HIDF * F_INF * 2);      // 64 KB
    int*    rowptr = (int*)alloc((size_t)(N_NODES + 1) * 4);
    int*    deg    = (int*)alloc((size_t)N_NODES * 4);
    int*    cursor = (int*)alloc((size_t)N_NODES * 4);
    int2*   srcw   = (int2*)alloc((size_t)E_EDGES * 8);            // 25.6 MB

    hipMemsetAsync(deg, 0, (size_t)N_NODES * 4, stream);
    hipMemsetAsync(cursor, 0, (size_t)N_NODES * 4, stream);

    hist_kernel<<<4096, 256, 0, stream>>>(ei, deg);
    w1t_kernel<<<128, 256, 0, stream>>>(W1, w1t);
    scan_kernel<<<1, 1024, 0, stream>>>(deg, rowptr);
    fill_kernel<<<4096, 256, 0, stream>>>(ei, ew, rowptr, cursor, srcw);

    gemm1_kernel<<<(N_NODES + 127) / 128, 256, 0, stream>>>(x, w1t, h);
    agg1_kernel<<<(N_NODES + 3) / 4, 256, 0, stream>>>(h, srcw, rowptr, b1, hact);
    gemm2_kernel<<<(N_NODES + 63) / 64, 320, 0, stream>>>(hact, W2, h2);
    agg2_kernel<<<(N_NODES + 3) / 4, 256, 0, stream>>>(h2, srcw, rowptr, b2, out);
}

// Round 3
// 639.490 us; speedup vs baseline: 1.6117x; 1.2985x over previous
//
#include <hip/hip_runtime.h>
#include <hip/hip_bf16.h>
#include <hip/hip_fp16.h>
#include <math.h>

#define N_NODES 100000
#define E_EDGES 3200000
#define F_INF   256
#define HIDF    128
#define C_OUT   40

// bucketed CSR build params
#define BSH   8            // bucket = dst >> 8 (256 nodes per bucket)
#define NB    391          // ceil(100000/256)
#define NSEG  32
#define CAP   384          // per (seg,bucket) capacity; mean ~256, +8 sigma
#define OCAP  262144       // overflow list capacity
#define EPB   1563         // edges per block in scat (2048 blocks)

typedef __attribute__((ext_vector_type(8))) short bf16x8;
typedef __attribute__((ext_vector_type(4))) float f32x4;

static __device__ __forceinline__ short bf16c(float f) {
    __hip_bfloat16 b = __float2bfloat16(f);
    return *reinterpret_cast<short*>(&b);
}

// ---------------------------------------------------------------------------
// K1: scatter edges into (seg,bucket) streams. Appends are sequential per
// stream -> L2 lines fill completely before writeback (no 8x amplification).
// record = (src | dstlocal<<17, weight)
// ---------------------------------------------------------------------------
__global__ __launch_bounds__(256) void scat_kernel(const int* __restrict__ ei,
        const float* __restrict__ ew, int* __restrict__ cnt,
        int2* __restrict__ rec, int* __restrict__ ocnt,
        int2* __restrict__ osw, int* __restrict__ odst) {
    int bid = blockIdx.x;
    int seg = bid & (NSEG - 1);
    int e0 = bid * EPB;
    int e1 = e0 + EPB; if (e1 > E_EDGES) e1 = E_EDGES;
    for (int e = e0 + threadIdx.x; e < e1; e += 256) {
        int dst = ei[E_EDGES + e];
        int src = ei[e];
        float w = ew[e];
        int b = dst >> BSH;
        int packed = src | ((dst & 255) << 17);
        int pos = atomicAdd(&cnt[seg * NB + b], 1);
        if (pos < CAP) {
            rec[(size_t)(seg * NB + b) * CAP + pos] =
                make_int2(packed, __float_as_int(w));
        } else {
            int op = atomicAdd(ocnt, 1);
            if (op < OCAP) { osw[op] = make_int2(src, __float_as_int(w)); odst[op] = dst; }
        }
    }
}

// ---------------------------------------------------------------------------
// K3: one block per bucket. LDS histogram over 256 local nodes -> scan ->
// write rowptr -> scatter records into final CSR (contiguous ~128KB region,
// L2-resident -> full-line writebacks). Also replaces hist/scan kernels.
// ---------------------------------------------------------------------------
__global__ __launch_bounds__(256) void csr_kernel(const int* __restrict__ cnt,
        const int2* __restrict__ rec, const int* __restrict__ ocnt,
        const int2* __restrict__ osw, const int* __restrict__ odst,
        int* __restrict__ rowptr, int2* __restrict__ srcw) {
    __shared__ int hist[256], sc[256], cur[256];
    __shared__ int red[4];
    __shared__ int s_base;
    int b = blockIdx.x, tid = threadIdx.x;
    hist[tid] = 0;

    // bucket base = sum of stored counts for buckets < b (+ overflow below b)
    int partial = 0;
    for (int i = tid; i < b * NSEG; i += 256) {
        int bp = i >> 5, s = i & 31;
        int c = cnt[s * NB + bp];
        partial += (c < CAP ? c : CAP);
    }
    int onum = *ocnt; if (onum > OCAP) onum = OCAP;
    for (int i = tid; i < onum; i += 256)
        if ((odst[i] >> BSH) < b) ++partial;
    #pragma unroll
    for (int off = 32; off; off >>= 1) partial += __shfl_xor(partial, off);
    if ((tid & 63) == 0) red[tid >> 6] = partial;
    __syncthreads();
    if (tid == 0) s_base = red[0] + red[1] + red[2] + red[3];
    __syncthreads();

    // phase A: histogram of local dst
    for (int s = 0; s < NSEG; ++s) {
        int c = cnt[s * NB + b]; if (c > CAP) c = CAP;
        const int2* rp = &rec[(size_t)(s * NB + b) * CAP];
        for (int i = tid; i < c; i += 256)
            atomicAdd(&hist[(rp[i].x >> 17) & 255], 1);
    }
    for (int i = tid; i < onum; i += 256) {
        int d = odst[i];
        if ((d >> BSH) == b) atomicAdd(&hist[d & 255], 1);
    }
    __syncthreads();

    // inclusive scan (Hillis-Steele, 256)
    sc[tid] = hist[tid];
    __syncthreads();
    for (int off = 1; off < 256; off <<= 1) {
        int v = (tid >= off) ? sc[tid - off] : 0;
        __syncthreads();
        sc[tid] += v;
        __syncthreads();
    }
    int excl = (tid > 0) ? sc[tid - 1] : 0;
    cur[tid] = excl;
    int base = s_base;
    int node = b * 256 + tid;
    if (node <= N_NODES) rowptr[node] = base + excl;   // covers rowptr[N] too
    __syncthreads();

    // phase C: scatter into final CSR
    for (int s = 0; s < NSEG; ++s) {
        int c = cnt[s * NB + b]; if (c > CAP) c = CAP;
        const int2* rp = &rec[(size_t)(s * NB + b) * CAP];
        for (int i = tid; i < c; i += 256) {
            int2 r = rp[i];
            int dl = (r.x >> 17) & 255;
            int p = atomicAdd(&cur[dl], 1);
            srcw[base + p] = make_int2(r.x & 0x1FFFF, r.y);
        }
    }
    for (int i = tid; i < onum; i += 256) {
        int d = odst[i];
        if ((d >> BSH) == b) {
            int p = atomicAdd(&cur[d & 255], 1);
            srcw[base + p] = osw[i];
        }
    }
}

// ---------------------------------------------------------------------------
// W1T precompute: W1[256,128] f32 -> W1T[128,256] bf16 (stays L2-resident)
// ---------------------------------------------------------------------------
__global__ void w1t_kernel(const float* __restrict__ W1, short* __restrict__ w1t) {
    int idx = blockIdx.x * 256 + threadIdx.x;  // 0..32767
    int k = idx >> 7, c = idx & 127;
    w1t[c * 256 + k] = bf16c(W1[idx]);
}

// ---------------------------------------------------------------------------
// GEMM1 (MFMA bf16): h[100000,128]fp16 = x[100000,256] @ W1
// 128x128 tile, 4 waves (2x2), BK=64, A in swizzled LDS, B direct from L2.
// ---------------------------------------------------------------------------
__global__ __launch_bounds__(256) void gemm1_kernel(const float* __restrict__ x,
                                                    const short* __restrict__ w1t,
                                                    __half* __restrict__ h) {
    __shared__ short aT[128 * 64];  // [row][k] bf16, XOR-swizzled, 16 KB
    int tid = threadIdx.x;
    int lane = tid & 63, wid = tid >> 6;
    int wr = wid >> 1, wc = wid & 1;
    int m0 = blockIdx.x * 128;
    f32x4 acc[4][4] = {{{0.f}}};
    for (int kb = 0; kb < 256; kb += 64) {
        #pragma unroll
        for (int t = 0; t < 8; ++t) {              // stage A tile, cvt f32->bf16
            int id = tid + t * 256;                // 0..2047: row(128) x chunk4(16)
            int row = id >> 4, c4 = id & 15;
            int gr = m0 + row; if (gr >= N_NODES) gr = N_NODES - 1;
            float4 g = *(const float4*)&x[(size_t)gr * F_INF + kb + c4 * 4];
            short4 s4 = { bf16c(g.x), bf16c(g.y), bf16c(g.z), bf16c(g.w) };
            int byte = row * 128 + c4 * 8;
            byte ^= (row & 7) << 4;
            *(short4*)((char*)aT + byte) = s4;
        }
        __syncthreads();
        #pragma unroll
        for (int km = 0; km < 2; ++km) {
            bf16x8 af[4], bfr[4];
            #pragma unroll
            for (int mi = 0; mi < 4; ++mi) {
                int row = wr * 64 + mi * 16 + (lane & 15);
                int kk = km * 32 + (lane >> 4) * 8;
                int byte = row * 128 + kk * 2;
                byte ^= (row & 7) << 4;
                af[mi] = *(bf16x8*)((char*)aT + byte);
            }
            #pragma unroll
            for (int ni = 0; ni < 4; ++ni) {
                int col = wc * 64 + ni * 16 + (lane & 15);
                int kk = kb + km * 32 + (lane >> 4) * 8;
                bfr[ni] = *(const bf16x8*)&w1t[col * 256 + kk];
            }
            #pragma unroll
            for (int mi = 0; mi < 4; ++mi)
                #pragma unroll
                for (int ni = 0; ni < 4; ++ni)
                    acc[mi][ni] = __builtin_amdgcn_mfma_f32_16x16x32_bf16(
                        af[mi], bfr[ni], acc[mi][ni], 0, 0, 0);
        }
        __syncthreads();
    }
    // C/D: col = lane&15, row = (lane>>4)*4 + r
    #pragma unroll
    for (int mi = 0; mi < 4; ++mi) {
        int rbase = m0 + wr * 64 + mi * 16 + ((lane >> 4) << 2);
        #pragma unroll
        for (int ni = 0; ni < 4; ++ni) {
            int col = wc * 64 + ni * 16 + (lane & 15);
            #pragma unroll
            for (int r = 0; r < 4; ++r) {
                int row = rbase + r;
                if (row < N_NODES)
                    h[(size_t)row * HIDF + col] = __float2half(acc[mi][ni][r]);
            }
        }
    }
}

// ---------------------------------------------------------------------------
// agg1: per-node wave CSR gather, 2 edges/iter (lane = eo*32+fo), fp16 h,
// fused +b1 + relu, fp16 hact out.
// ---------------------------------------------------------------------------
__global__ __launch_bounds__(256) void agg1_kernel(const __half* __restrict__ h,
                                                   const int2* __restrict__ srcw,
                                                   const int* __restrict__ rowptr,
                                                   const float* __restrict__ b1,
                                                   __half* __restrict__ hact) {
    int lane = threadIdx.x & 63;
    int node = blockIdx.x * 4 + (threadIdx.x >> 6);
    if (node >= N_NODES) return;
    int beg = rowptr[node], end = rowptr[node + 1];
    int eo = lane >> 5, fo = lane & 31;          // edge-offset, feature quad
    float4 acc = {0.f, 0.f, 0.f, 0.f};
    const uint2* hp = (const uint2*)h;           // row = 32 x uint2 (4 halfs)
    for (int base = beg; base < end; base += 64) {
        int idx = base + lane;
        int2 sw = srcw[idx < end ? idx : end - 1];
        int cnt = end - base; if (cnt > 64) cnt = 64;
        for (int j = 0; j < cnt; j += 2) {
            int jj = j + eo;
            int s = __shfl(sw.x, jj);
            float w = __int_as_float(__shfl(sw.y, jj));
            if (jj >= cnt) w = 0.f;
            uint2 hv = hp[(size_t)s * 32 + fo];
            float2 f01 = __half22float2(*(__half2*)&hv.x);
            float2 f23 = __half22float2(*(__half2*)&hv.y);
            acc.x += w * f01.x; acc.y += w * f01.y;
            acc.z += w * f23.x; acc.w += w * f23.y;
        }
    }
    acc.x += __shfl_xor(acc.x, 32);
    acc.y += __shfl_xor(acc.y, 32);
    acc.z += __shfl_xor(acc.z, 32);
    acc.w += __shfl_xor(acc.w, 32);
    if (lane < 32) {
        float4 bb = ((const float4*)b1)[fo];
        __half2 o01 = __floats2half2_rn(fmaxf(acc.x + bb.x, 0.f),
                                        fmaxf(acc.y + bb.y, 0.f));
        __half2 o23 = __floats2half2_rn(fmaxf(acc.z + bb.z, 0.f),
                                        fmaxf(acc.w + bb.w, 0.f));
        uint2 ov = { *(uint*)&o01, *(uint*)&o23 };
        ((uint2*)hact)[(size_t)node * 32 + fo] = ov;
    }
}

// ---------------------------------------------------------------------------
// GEMM2: h2[100000,40]fp16 = hact[100000,128]fp16 @ W2[128,40]
// ---------------------------------------------------------------------------
__global__ __launch_bounds__(320) void gemm2_kernel(const __half* __restrict__ hact,
                                                    const float* __restrict__ W2,
                                                    __half* __restrict__ h2) {
    __shared__ float xT[128 * 68];   // [k][row]
    __shared__ float w2[128 * 40];
    int tid = threadIdx.x;
    int tx = tid % 40, ty = tid / 40;
    int m0 = blockIdx.x * 64;
    for (int i = tid; i < 128 * 40; i += 320) w2[i] = W2[i];
    for (int i = tid; i < 1024; i += 320) {       // 64 rows x 16 chunks(8 halfs)
        int row = i >> 4, c8 = i & 15;
        int gr = m0 + row; if (gr >= N_NODES) gr = N_NODES - 1;
        uint4 v = *(const uint4*)&hact[(size_t)gr * HIDF + c8 * 8];
        const __half2* ph = (const __half2*)&v;
        #pragma unroll
        for (int t = 0; t < 4; ++t) {
            float2 f = __half22float2(ph[t]);
            int k = c8 * 8 + t * 2;
            xT[(k + 0) * 68 + row] = f.x;
            xT[(k + 1) * 68 + row] = f.y;
        }
    }
    __syncthreads();
    float acc[8] = {};
    #pragma unroll 4
    for (int k = 0; k < 128; ++k) {
        float wv = w2[k * 40 + tx];
        float4 xa = *(float4*)&xT[k * 68 + ty * 8];
        float4 xb = *(float4*)&xT[k * 68 + ty * 8 + 4];
        acc[0] += xa.x * wv; acc[1] += xa.y * wv;
        acc[2] += xa.z * wv; acc[3] += xa.w * wv;
        acc[4] += xb.x * wv; acc[5] += xb.y * wv;
        acc[6] += xb.z * wv; acc[7] += xb.w * wv;
    }
    #pragma unroll
    for (int i = 0; i < 8; ++i) {
        int r = m0 + ty * 8 + i;
        if (r < N_NODES) h2[(size_t)r * C_OUT + tx] = __float2half(acc[i]);
    }
}

// ---------------------------------------------------------------------------
// agg2: per-node wave CSR gather (2 edges/iter), fp16 h2, fused +b2 +
// log_softmax (40 classes), f32 out.
// ---------------------------------------------------------------------------
__global__ __launch_bounds__(256) void agg2_kernel(const __half* __restrict__ h2,
                                                   const int2* __restrict__ srcw,
                                                   const int* __restrict__ rowptr,
                                                   const float* __restrict__ b2,
                                                   float* __restrict__ out) {
    int lane = threadIdx.x & 63;
    int node = blockIdx.x * 4 + (threadIdx.x >> 6);
    if (node >= N_NODES) return;
    int beg = rowptr[node], end = rowptr[node + 1];
    int eo = lane >> 5, co = lane & 31;          // co: class pair 0..19 valid
    float2 acc = {0.f, 0.f};
    const uint* h2p = (const uint*)h2;           // row = 20 x uint (half2)
    for (int base = beg; base < end; base += 64) {
        int idx = base + lane;
        int2 sw = srcw[idx < end ? idx : end - 1];
        int cnt = end - base; if (cnt > 64) cnt = 64;
        for (int j = 0; j < cnt; j += 2) {
            int jj = j + eo;
            int s = __shfl(sw.x, jj);
            float w = __int_as_float(__shfl(sw.y, jj));
            if (jj >= cnt) w = 0.f;
            if (co < 20) {
                uint hv = h2p[(size_t)s * 20 + co];
                float2 f = __half22float2(*(__half2*)&hv);
                acc.x += w * f.x; acc.y += w * f.y;
            }
        }
    }
    acc.x += __shfl_xor(acc.x, 32);
    acc.y += __shfl_xor(acc.y, 32);
    float v0 = -INFINITY, v1 = -INFINITY;
    if (co < 20) {
        v0 = acc.x + b2[co * 2];
        v1 = acc.y + b2[co * 2 + 1];
    }
    float m = fmaxf(v0, v1);
    #pragma unroll
    for (int off = 32; off; off >>= 1) m = fmaxf(m, __shfl_xor(m, off));
    float ex = (co < 20 && eo == 0) ? (expf(v0 - m) + expf(v1 - m)) : 0.f;
    #pragma unroll
    for (int off = 32; off; off >>= 1) ex += __shfl_xor(ex, off);
    float ls = logf(ex);
    if (co < 20 && eo == 0) {
        float2 o = { v0 - m - ls, v1 - m - ls };
        ((float2*)out)[(size_t)node * 20 + co] = o;
    }
}

// ---------------------------------------------------------------------------

extern "C" void kernel_launch(void* const* d_in, const int* in_sizes, int n_in,
                              void* d_out, int out_size, void* d_ws, size_t ws_size,
                              hipStream_t stream) {
    const float* x  = (const float*)d_in[0];
    const int*   ei = (const int*)d_in[1];      // [2,E]: row0=src, row1=dst
    const float* ew = (const float*)d_in[2];
    const float* W1 = (const float*)d_in[3];
    const float* b1 = (const float*)d_in[4];
    const float* W2 = (const float*)d_in[5];
    const float* b2 = (const float*)d_in[6];
    float* out = (float*)d_out;

    char* ws = (char*)d_ws;
    size_t off = 0;
    auto alloc = [&](size_t bytes) -> void* {
        void* p = ws + off;
        off += (bytes + 255) & ~(size_t)255;
        return p;
    };
    __half* h      = (__half*)alloc((size_t)N_NODES * HIDF * 2);     // 25.6 MB
    __half* hact   = (__half*)alloc((size_t)N_NODES * HIDF * 2);     // 25.6 MB
    __half* h2     = (__half*)alloc((size_t)N_NODES * C_OUT * 2);    // 8 MB
    short*  w1t    = (short*)alloc((size_t)HIDF * F_INF * 2);        // 64 KB
    int*    rowptr = (int*)alloc((size_t)(N_NODES + 1) * 4);
    int2*   srcw   = (int2*)alloc((size_t)E_EDGES * 8);              // 25.6 MB
    int2*   rec    = (int2*)alloc((size_t)NSEG * NB * CAP * 8);      // 38.4 MB
    int*    cnt    = (int*)alloc((size_t)NSEG * NB * 4);             // 50 KB
    int*    ocnt   = (int*)alloc(256);
    int2*   osw    = (int2*)alloc((size_t)OCAP * 8);                 // 2 MB
    int*    odst   = (int*)alloc((size_t)OCAP * 4);                  // 1 MB

    hipMemsetAsync(cnt, 0, (size_t)NSEG * NB * 4, stream);
    hipMemsetAsync(ocnt, 0, 4, stream);

    scat_kernel<<<2048, 256, 0, stream>>>(ei, ew, cnt, rec, ocnt, osw, odst);
    csr_kernel<<<NB, 256, 0, stream>>>(cnt, rec, ocnt, osw, odst, rowptr, srcw);

    w1t_kernel<<<128, 256, 0, stream>>>(W1, w1t);
    gemm1_kernel<<<(N_NODES + 127) / 128, 256, 0, stream>>>(x, w1t, h);
    agg1_kernel<<<(N_NODES + 3) / 4, 256, 0, stream>>>(h, srcw, rowptr, b1, hact);
    gemm2_kernel<<<(N_NODES + 63) / 64, 320, 0, stream>>>(hact, W2, h2);
    agg2_kernel<<<(N_NODES + 3) / 4, 256, 0, stream>>>(h2, srcw, rowptr, b2, out);
}

// Round 4
// 559.529 us; speedup vs baseline: 1.8420x; 1.1429x over previous
//
#include <hip/hip_runtime.h>
#include <hip/hip_bf16.h>
#include <hip/hip_fp16.h>
#include <math.h>

#define N_NODES 100000
#define E_EDGES 3200000
#define F_INF   256
#define HIDF    128
#define C_OUT   40

// bucketed CSR build params
#define BSH   8            // bucket = dst >> 8 (256 nodes per bucket)
#define NB    391          // ceil(100000/256)
#define NSEG  32
#define CAP   384          // per (seg,bucket) capacity; mean ~256, +8 sigma
#define OCAP  262144       // overflow list capacity
#define EPB   1563         // edges per block in scat (2048 blocks)
#define SCAT_BLOCKS 2048
#define W1T_BLOCKS  128
#define GEMM1_BLOCKS ((N_NODES + 127) / 128)

typedef __attribute__((ext_vector_type(8))) short bf16x8;
typedef __attribute__((ext_vector_type(4))) float f32x4;

static __device__ __forceinline__ short bf16c(float f) {
    __hip_bfloat16 b = __float2bfloat16(f);
    return *reinterpret_cast<short*>(&b);
}

// ---------------------------------------------------------------------------
// scat body: scatter edges into (seg,bucket) streams (L2-line-friendly).
// seg = bid&31 keeps each stream's writers on one XCD (bid%8 fixed).
// ---------------------------------------------------------------------------
static __device__ void scat_body(int bid, const int* __restrict__ ei,
        const float* __restrict__ ew, int* __restrict__ cnt,
        int2* __restrict__ rec, int* __restrict__ ocnt,
        int2* __restrict__ osw, int* __restrict__ odst) {
    int seg = bid & (NSEG - 1);
    int e0 = bid * EPB;
    int e1 = e0 + EPB; if (e1 > E_EDGES) e1 = E_EDGES;
    for (int e = e0 + threadIdx.x; e < e1; e += 256) {
        int dst = ei[E_EDGES + e];
        int src = ei[e];
        float w = ew[e];
        int b = dst >> BSH;
        int packed = src | ((dst & 255) << 17);
        int pos = atomicAdd(&cnt[seg * NB + b], 1);
        if (pos < CAP) {
            rec[(size_t)(seg * NB + b) * CAP + pos] =
                make_int2(packed, __float_as_int(w));
        } else {
            int op = atomicAdd(ocnt, 1);
            if (op < OCAP) { osw[op] = make_int2(src, __float_as_int(w)); odst[op] = dst; }
        }
    }
}

static __device__ void w1t_body(int bid, const float* __restrict__ W1,
                                short* __restrict__ w1t) {
    int idx = bid * 256 + threadIdx.x;  // 0..32767
    int k = idx >> 7, c = idx & 127;
    w1t[c * 256 + k] = bf16c(W1[idx]);
}

__global__ __launch_bounds__(256) void scat_w1t_kernel(const int* __restrict__ ei,
        const float* __restrict__ ew, int* __restrict__ cnt,
        int2* __restrict__ rec, int* __restrict__ ocnt,
        int2* __restrict__ osw, int* __restrict__ odst,
        const float* __restrict__ W1, short* __restrict__ w1t) {
    if (blockIdx.x < SCAT_BLOCKS)
        scat_body(blockIdx.x, ei, ew, cnt, rec, ocnt, osw, odst);
    else
        w1t_body(blockIdx.x - SCAT_BLOCKS, W1, w1t);
}

// ---------------------------------------------------------------------------
// csr body: one block per bucket -> rowptr + final CSR scatter (L2-resident)
// ---------------------------------------------------------------------------
static __device__ void csr_body(char* smem, int b, const int* __restrict__ cnt,
        const int2* __restrict__ rec, const int* __restrict__ ocnt,
        const int2* __restrict__ osw, const int* __restrict__ odst,
        int* __restrict__ rowptr, int2* __restrict__ srcw) {
    int* hist = (int*)smem;          // 256
    int* sc   = hist + 256;          // 256
    int* cur  = sc + 256;            // 256
    int* red  = cur + 256;           // 4
    int* s_base = red + 4;           // 1
    int tid = threadIdx.x;
    hist[tid] = 0;

    int partial = 0;
    for (int i = tid; i < b * NSEG; i += 256) {
        int bp = i >> 5, s = i & 31;
        int c = cnt[s * NB + bp];
        partial += (c < CAP ? c : CAP);
    }
    int onum = *ocnt; if (onum > OCAP) onum = OCAP;
    for (int i = tid; i < onum; i += 256)
        if ((odst[i] >> BSH) < b) ++partial;
    #pragma unroll
    for (int off = 32; off; off >>= 1) partial += __shfl_xor(partial, off);
    if ((tid & 63) == 0) red[tid >> 6] = partial;
    __syncthreads();
    if (tid == 0) *s_base = red[0] + red[1] + red[2] + red[3];
    __syncthreads();

    for (int s = 0; s < NSEG; ++s) {
        int c = cnt[s * NB + b]; if (c > CAP) c = CAP;
        const int2* rp = &rec[(size_t)(s * NB + b) * CAP];
        for (int i = tid; i < c; i += 256)
            atomicAdd(&hist[(rp[i].x >> 17) & 255], 1);
    }
    for (int i = tid; i < onum; i += 256) {
        int d = odst[i];
        if ((d >> BSH) == b) atomicAdd(&hist[d & 255], 1);
    }
    __syncthreads();

    sc[tid] = hist[tid];
    __syncthreads();
    for (int off = 1; off < 256; off <<= 1) {
        int v = (tid >= off) ? sc[tid - off] : 0;
        __syncthreads();
        sc[tid] += v;
        __syncthreads();
    }
    int excl = (tid > 0) ? sc[tid - 1] : 0;
    cur[tid] = excl;
    int base = *s_base;
    int node = b * 256 + tid;
    if (node <= N_NODES) rowptr[node] = base + excl;
    __syncthreads();

    for (int s = 0; s < NSEG; ++s) {
        int c = cnt[s * NB + b]; if (c > CAP) c = CAP;
        const int2* rp = &rec[(size_t)(s * NB + b) * CAP];
        for (int i = tid; i < c; i += 256) {
            int2 r = rp[i];
            int dl = (r.x >> 17) & 255;
            int p = atomicAdd(&cur[dl], 1);
            srcw[base + p] = make_int2(r.x & 0x1FFFF, r.y);
        }
    }
    for (int i = tid; i < onum; i += 256) {
        int d = odst[i];
        if ((d >> BSH) == b) {
            int p = atomicAdd(&cur[d & 255], 1);
            srcw[base + p] = osw[i];
        }
    }
}

// ---------------------------------------------------------------------------
// gemm1 body (MFMA bf16): h[100000,128]fp16 = x @ W1. 128x128 tile, 4 waves.
// ---------------------------------------------------------------------------
static __device__ void gemm1_body(char* smem, int bid, const float* __restrict__ x,
                                  const short* __restrict__ w1t,
                                  __half* __restrict__ h) {
    short* aT = (short*)smem;  // [row][k] bf16, XOR-swizzled, 16 KB
    int tid = threadIdx.x;
    int lane = tid & 63, wid = tid >> 6;
    int wr = wid >> 1, wc = wid & 1;
    int m0 = bid * 128;
    f32x4 acc[4][4] = {{{0.f}}};
    for (int kb = 0; kb < 256; kb += 64) {
        #pragma unroll
        for (int t = 0; t < 8; ++t) {
            int id = tid + t * 256;
            int row = id >> 4, c4 = id & 15;
            int gr = m0 + row; if (gr >= N_NODES) gr = N_NODES - 1;
            float4 g = *(const float4*)&x[(size_t)gr * F_INF + kb + c4 * 4];
            short4 s4 = { bf16c(g.x), bf16c(g.y), bf16c(g.z), bf16c(g.w) };
            int byte = row * 128 + c4 * 8;
            byte ^= (row & 7) << 4;
            *(short4*)(smem + byte) = s4;
        }
        __syncthreads();
        #pragma unroll
        for (int km = 0; km < 2; ++km) {
            bf16x8 af[4], bfr[4];
            #pragma unroll
            for (int mi = 0; mi < 4; ++mi) {
                int row = wr * 64 + mi * 16 + (lane & 15);
                int kk = km * 32 + (lane >> 4) * 8;
                int byte = row * 128 + kk * 2;
                byte ^= (row & 7) << 4;
                af[mi] = *(bf16x8*)(smem + byte);
            }
            #pragma unroll
            for (int ni = 0; ni < 4; ++ni) {
                int col = wc * 64 + ni * 16 + (lane & 15);
                int kk = kb + km * 32 + (lane >> 4) * 8;
                bfr[ni] = *(const bf16x8*)&w1t[col * 256 + kk];
            }
            #pragma unroll
            for (int mi = 0; mi < 4; ++mi)
                #pragma unroll
                for (int ni = 0; ni < 4; ++ni)
                    acc[mi][ni] = __builtin_amdgcn_mfma_f32_16x16x32_bf16(
                        af[mi], bfr[ni], acc[mi][ni], 0, 0, 0);
        }
        __syncthreads();
    }
    #pragma unroll
    for (int mi = 0; mi < 4; ++mi) {
        int rbase = m0 + wr * 64 + mi * 16 + ((lane >> 4) << 2);
        #pragma unroll
        for (int ni = 0; ni < 4; ++ni) {
            int col = wc * 64 + ni * 16 + (lane & 15);
            #pragma unroll
            for (int r = 0; r < 4; ++r) {
                int row = rbase + r;
                if (row < N_NODES)
                    h[(size_t)row * HIDF + col] = __float2half(acc[mi][ni][r]);
            }
        }
    }
}

__global__ __launch_bounds__(256) void csr_gemm1_kernel(const int* __restrict__ cnt,
        const int2* __restrict__ rec, const int* __restrict__ ocnt,
        const int2* __restrict__ osw, const int* __restrict__ odst,
        int* __restrict__ rowptr, int2* __restrict__ srcw,
        const float* __restrict__ x, const short* __restrict__ w1t,
        __half* __restrict__ h) {
    __shared__ char smem[16384];
    if (blockIdx.x < NB)
        csr_body(smem, blockIdx.x, cnt, rec, ocnt, osw, odst, rowptr, srcw);
    else
        gemm1_body(smem, blockIdx.x - NB, x, w1t, h);
}

// ---------------------------------------------------------------------------
// agg1: per-node wave CSR gather, 4 edges x 16 uint4-chunks per iter, 2x
// unrolled (8 edges in flight). fused +b1 + relu, fp16 out.
// ---------------------------------------------------------------------------
__global__ __launch_bounds__(256) void agg1_kernel(const __half* __restrict__ h,
                                                   const int2* __restrict__ srcw,
                                                   const int* __restrict__ rowptr,
                                                   const float* __restrict__ b1,
                                                   __half* __restrict__ hact) {
    int lane = threadIdx.x & 63;
    int node = blockIdx.x * 4 + (threadIdx.x >> 6);
    if (node >= N_NODES) return;
    int beg = rowptr[node], end = rowptr[node + 1];
    int eo = lane >> 4, fo = lane & 15;          // 4 edges x 16 chunks(8 halfs)
    float4 a0 = {0.f, 0.f, 0.f, 0.f}, a1 = {0.f, 0.f, 0.f, 0.f};
    const uint4* hp = (const uint4*)h;           // row = 16 x uint4
    for (int base = beg; base < end; base += 64) {
        int idx = base + lane;
        int2 sw = srcw[idx < end ? idx : end - 1];
        int cnt = end - base; if (cnt > 64) cnt = 64;
        for (int j = 0; j < cnt; j += 8) {
            int jj0 = j + eo, jj1 = j + 4 + eo;
            int s0 = __shfl(sw.x, jj0);
            float w0 = __int_as_float(__shfl(sw.y, jj0));
            int s1 = __shfl(sw.x, jj1);
            float w1 = __int_as_float(__shfl(sw.y, jj1));
            if (jj0 >= cnt) w0 = 0.f;
            if (jj1 >= cnt) w1 = 0.f;
            uint4 hv0 = hp[(size_t)s0 * 16 + fo];
            uint4 hv1 = hp[(size_t)s1 * 16 + fo];
            const __half2* p0 = (const __half2*)&hv0;
            const __half2* p1 = (const __half2*)&hv1;
            float2 f;
            f = __half22float2(p0[0]); a0.x += w0 * f.x; a0.y += w0 * f.y;
            f = __half22float2(p0[1]); a0.z += w0 * f.x; a0.w += w0 * f.y;
            f = __half22float2(p0[2]); a1.x += w0 * f.x; a1.y += w0 * f.y;
            f = __half22float2(p0[3]); a1.z += w0 * f.x; a1.w += w0 * f.y;
            f = __half22float2(p1[0]); a0.x += w1 * f.x; a0.y += w1 * f.y;
            f = __half22float2(p1[1]); a0.z += w1 * f.x; a0.w += w1 * f.y;
            f = __half22float2(p1[2]); a1.x += w1 * f.x; a1.y += w1 * f.y;
            f = __half22float2(p1[3]); a1.z += w1 * f.x; a1.w += w1 * f.y;
        }
    }
    #pragma unroll
    for (int off = 16; off < 64; off <<= 1) {
        a0.x += __shfl_xor(a0.x, off); a0.y += __shfl_xor(a0.y, off);
        a0.z += __shfl_xor(a0.z, off); a0.w += __shfl_xor(a0.w, off);
        a1.x += __shfl_xor(a1.x, off); a1.y += __shfl_xor(a1.y, off);
        a1.z += __shfl_xor(a1.z, off); a1.w += __shfl_xor(a1.w, off);
    }
    if (lane < 16) {
        float4 bb0 = *(const float4*)&b1[fo * 8];
        float4 bb1 = *(const float4*)&b1[fo * 8 + 4];
        __half2 o0 = __floats2half2_rn(fmaxf(a0.x + bb0.x, 0.f), fmaxf(a0.y + bb0.y, 0.f));
        __half2 o1 = __floats2half2_rn(fmaxf(a0.z + bb0.z, 0.f), fmaxf(a0.w + bb0.w, 0.f));
        __half2 o2 = __floats2half2_rn(fmaxf(a1.x + bb1.x, 0.f), fmaxf(a1.y + bb1.y, 0.f));
        __half2 o3 = __floats2half2_rn(fmaxf(a1.z + bb1.z, 0.f), fmaxf(a1.w + bb1.w, 0.f));
        uint4 ov = { *(uint*)&o0, *(uint*)&o1, *(uint*)&o2, *(uint*)&o3 };
        ((uint4*)hact)[(size_t)node * 16 + fo] = ov;
    }
}

// ---------------------------------------------------------------------------
// GEMM2: h2[100000,40]fp16 = hact[100000,128]fp16 @ W2[128,40]
// ---------------------------------------------------------------------------
__global__ __launch_bounds__(320) void gemm2_kernel(const __half* __restrict__ hact,
                                                    const float* __restrict__ W2,
                                                    __half* __restrict__ h2) {
    __shared__ float xT[128 * 68];   // [k][row]
    __shared__ float w2[128 * 40];
    int tid = threadIdx.x;
    int tx = tid % 40, ty = tid / 40;
    int m0 = blockIdx.x * 64;
    for (int i = tid; i < 128 * 40; i += 320) w2[i] = W2[i];
    for (int i = tid; i < 1024; i += 320) {
        int row = i >> 4, c8 = i & 15;
        int gr = m0 + row; if (gr >= N_NODES) gr = N_NODES - 1;
        uint4 v = *(const uint4*)&hact[(size_t)gr * HIDF + c8 * 8];
        const __half2* ph = (const __half2*)&v;
        #pragma unroll
        for (int t = 0; t < 4; ++t) {
            float2 f = __half22float2(ph[t]);
            int k = c8 * 8 + t * 2;
            xT[(k + 0) * 68 + row] = f.x;
            xT[(k + 1) * 68 + row] = f.y;
        }
    }
    __syncthreads();
    float acc[8] = {};
    #pragma unroll 4
    for (int k = 0; k < 128; ++k) {
        float wv = w2[k * 40 + tx];
        float4 xa = *(float4*)&xT[k * 68 + ty * 8];
        float4 xb = *(float4*)&xT[k * 68 + ty * 8 + 4];
        acc[0] += xa.x * wv; acc[1] += xa.y * wv;
        acc[2] += xa.z * wv; acc[3] += xa.w * wv;
        acc[4] += xb.x * wv; acc[5] += xb.y * wv;
        acc[6] += xb.z * wv; acc[7] += xb.w * wv;
    }
    #pragma unroll
    for (int i = 0; i < 8; ++i) {
        int r = m0 + ty * 8 + i;
        if (r < N_NODES) h2[(size_t)r * C_OUT + tx] = __float2half(acc[i]);
    }
}

// ---------------------------------------------------------------------------
// agg2: per-node wave CSR gather, 4 edges x 10 uint2-chunks per iter, 2x
// unrolled. fused +b2 + log_softmax (40 classes), f32 out.
// ---------------------------------------------------------------------------
__global__ __launch_bounds__(256) void agg2_kernel(const __half* __restrict__ h2,
                                                   const int2* __restrict__ srcw,
                                                   const int* __restrict__ rowptr,
                                                   const float* __restrict__ b2,
                                                   float* __restrict__ out) {
    int lane = threadIdx.x & 63;
    int node = blockIdx.x * 4 + (threadIdx.x >> 6);
    if (node >= N_NODES) return;
    int beg = rowptr[node], end = rowptr[node + 1];
    int eo = lane >> 4, fo = lane & 15;          // 4 edges x 10 chunks(4 halfs)
    float4 acc = {0.f, 0.f, 0.f, 0.f};
    const uint2* hp = (const uint2*)h2;          // row = 10 x uint2
    for (int base = beg; base < end; base += 64) {
        int idx = base + lane;
        int2 sw = srcw[idx < end ? idx : end - 1];
        int cnt = end - base; if (cnt > 64) cnt = 64;
        for (int j = 0; j < cnt; j += 8) {
            int jj0 = j + eo, jj1 = j + 4 + eo;
            int s0 = __shfl(sw.x, jj0);
            float w0 = __int_as_float(__shfl(sw.y, jj0));
            int s1 = __shfl(sw.x, jj1);
            float w1 = __int_as_float(__shfl(sw.y, jj1));
            if (jj0 >= cnt) w0 = 0.f;
            if (jj1 >= cnt) w1 = 0.f;
            if (fo < 10) {
                uint2 hv0 = hp[(size_t)s0 * 10 + fo];
                uint2 hv1 = hp[(size_t)s1 * 10 + fo];
                float2 f;
                f = __half22float2(*(__half2*)&hv0.x); acc.x += w0 * f.x; acc.y += w0 * f.y;
                f = __half22float2(*(__half2*)&hv0.y); acc.z += w0 * f.x; acc.w += w0 * f.y;
                f = __half22float2(*(__half2*)&hv1.x); acc.x += w1 * f.x; acc.y += w1 * f.y;
                f = __half22float2(*(__half2*)&hv1.y); acc.z += w1 * f.x; acc.w += w1 * f.y;
            }
        }
    }
    #pragma unroll
    for (int off = 16; off < 64; off <<= 1) {
        acc.x += __shfl_xor(acc.x, off); acc.y += __shfl_xor(acc.y, off);
        acc.z += __shfl_xor(acc.z, off); acc.w += __shfl_xor(acc.w, off);
    }
    float4 v = {-INFINITY, -INFINITY, -INFINITY, -INFINITY};
    if (fo < 10) {
        float4 bb = *(const float4*)&b2[fo * 4];
        v.x = acc.x + bb.x; v.y = acc.y + bb.y;
        v.z = acc.z + bb.z; v.w = acc.w + bb.w;
    }
    float m = fmaxf(fmaxf(v.x, v.y), fmaxf(v.z, v.w));
    #pragma unroll
    for (int off = 8; off; off >>= 1) m = fmaxf(m, __shfl_xor(m, off));
    float ex = 0.f;
    if (fo < 10)
        ex = expf(v.x - m) + expf(v.y - m) + expf(v.z - m) + expf(v.w - m);
    #pragma unroll
    for (int off = 8; off; off >>= 1) ex += __shfl_xor(ex, off);
    float ls = logf(ex);
    if (lane < 16 && fo < 10) {
        float4 o = { v.x - m - ls, v.y - m - ls, v.z - m - ls, v.w - m - ls };
        *(float4*)&out[(size_t)node * C_OUT + fo * 4] = o;
    }
}

// ---------------------------------------------------------------------------

extern "C" void kernel_launch(void* const* d_in, const int* in_sizes, int n_in,
                              void* d_out, int out_size, void* d_ws, size_t ws_size,
                              hipStream_t stream) {
    const float* x  = (const float*)d_in[0];
    const int*   ei = (const int*)d_in[1];      // [2,E]: row0=src, row1=dst
    const float* ew = (const float*)d_in[2];
    const float* W1 = (const float*)d_in[3];
    const float* b1 = (const float*)d_in[4];
    const float* W2 = (const float*)d_in[5];
    const float* b2 = (const float*)d_in[6];
    float* out = (float*)d_out;

    char* ws = (char*)d_ws;
    size_t off = 0;
    auto alloc = [&](size_t bytes) -> void* {
        void* p = ws + off;
        off += (bytes + 255) & ~(size_t)255;
        return p;
    };
    __half* h      = (__half*)alloc((size_t)N_NODES * HIDF * 2);     // 25.6 MB
    __half* hact   = (__half*)alloc((size_t)N_NODES * HIDF * 2);     // 25.6 MB
    __half* h2     = (__half*)alloc((size_t)N_NODES * C_OUT * 2);    // 8 MB
    short*  w1t    = (short*)alloc((size_t)HIDF * F_INF * 2);        // 64 KB
    int*    rowptr = (int*)alloc((size_t)(N_NODES + 1) * 4);
    int2*   srcw   = (int2*)alloc((size_t)E_EDGES * 8);              // 25.6 MB
    int2*   rec    = (int2*)alloc((size_t)NSEG * NB * CAP * 8);      // 38.4 MB
    int*    cnt    = (int*)alloc((size_t)NSEG * NB * 4);             // 50 KB
    int*    ocnt   = (int*)alloc(256);
    int2*   osw    = (int2*)alloc((size_t)OCAP * 8);                 // 2 MB
    int*    odst   = (int*)alloc((size_t)OCAP * 4);                  // 1 MB

    hipMemsetAsync(cnt, 0, (size_t)NSEG * NB * 4, stream);
    hipMemsetAsync(ocnt, 0, 4, stream);

    scat_w1t_kernel<<<SCAT_BLOCKS + W1T_BLOCKS, 256, 0, stream>>>(
        ei, ew, cnt, rec, ocnt, osw, odst, W1, w1t);
    csr_gemm1_kernel<<<NB + GEMM1_BLOCKS, 256, 0, stream>>>(
        cnt, rec, ocnt, osw, odst, rowptr, srcw, x, w1t, h);
    agg1_kernel<<<(N_NODES + 3) / 4, 256, 0, stream>>>(h, srcw, rowptr, b1, hact);
    gemm2_kernel<<<(N_NODES + 63) / 64, 320, 0, stream>>>(hact, W2, h2);
    agg2_kernel<<<(N_NODES + 3) / 4, 256, 0, stream>>>(h2, srcw, rowptr, b2, out);
}

// Round 5
// 548.450 us; speedup vs baseline: 1.8793x; 1.0202x over previous
//
#include <hip/hip_runtime.h>
#include <hip/hip_bf16.h>
#include <hip/hip_fp16.h>
#include <math.h>

#define N_NODES 100000
#define E_EDGES 3200000
#define F_INF   256
#define HIDF    128
#define C_OUT   40
#define H2P     64         // padded h2 row (fp16)

// bucketed CSR build params
#define BSH   8            // bucket = dst >> 8 (256 nodes per bucket)
#define NB    391          // ceil(100000/256)
#define NSEG  32
#define CAP   384          // per (seg,bucket) capacity; mean ~256, +8 sigma
#define OCAP  262144       // overflow list capacity
#define EPB   1563         // edges per block in scat (2048 blocks)
#define SCAT_BLOCKS 2048
#define W1T_BLOCKS  128
#define GEMM1_BLOCKS ((N_NODES + 127) / 128)

typedef __attribute__((ext_vector_type(8))) short bf16x8;
typedef __attribute__((ext_vector_type(4))) float f32x4;

static __device__ __forceinline__ short bf16c(float f) {
    __hip_bfloat16 b = __float2bfloat16(f);
    return *reinterpret_cast<short*>(&b);
}

// ---------------------------------------------------------------------------
// scat body: scatter edges into (seg,bucket) streams (L2-line-friendly).
// ---------------------------------------------------------------------------
static __device__ void scat_body(int bid, const int* __restrict__ ei,
        const float* __restrict__ ew, int* __restrict__ cnt,
        int2* __restrict__ rec, int* __restrict__ ocnt,
        int2* __restrict__ osw, int* __restrict__ odst) {
    int seg = bid & (NSEG - 1);
    int e0 = bid * EPB;
    int e1 = e0 + EPB; if (e1 > E_EDGES) e1 = E_EDGES;
    for (int e = e0 + threadIdx.x; e < e1; e += 256) {
        int dst = ei[E_EDGES + e];
        int src = ei[e];
        float w = ew[e];
        int b = dst >> BSH;
        int packed = src | ((dst & 255) << 17);
        int pos = atomicAdd(&cnt[seg * NB + b], 1);
        if (pos < CAP) {
            rec[(size_t)(seg * NB + b) * CAP + pos] =
                make_int2(packed, __float_as_int(w));
        } else {
            int op = atomicAdd(ocnt, 1);
            if (op < OCAP) { osw[op] = make_int2(src, __float_as_int(w)); odst[op] = dst; }
        }
    }
}

static __device__ void w1t_body(int bid, const float* __restrict__ W1,
                                short* __restrict__ w1t) {
    int idx = bid * 256 + threadIdx.x;  // 0..32767
    int k = idx >> 7, c = idx & 127;
    w1t[c * 256 + k] = bf16c(W1[idx]);
}

__global__ __launch_bounds__(256) void scat_w1t_kernel(const int* __restrict__ ei,
        const float* __restrict__ ew, int* __restrict__ cnt,
        int2* __restrict__ rec, int* __restrict__ ocnt,
        int2* __restrict__ osw, int* __restrict__ odst,
        const float* __restrict__ W1, short* __restrict__ w1t) {
    if (blockIdx.x < SCAT_BLOCKS)
        scat_body(blockIdx.x, ei, ew, cnt, rec, ocnt, osw, odst);
    else
        w1t_body(blockIdx.x - SCAT_BLOCKS, W1, w1t);
}

// ---------------------------------------------------------------------------
// csr body: one block per bucket -> rowptr + final CSR scatter (L2-resident)
// ---------------------------------------------------------------------------
static __device__ void csr_body(char* smem, int b, const int* __restrict__ cnt,
        const int2* __restrict__ rec, const int* __restrict__ ocnt,
        const int2* __restrict__ osw, const int* __restrict__ odst,
        int* __restrict__ rowptr, int2* __restrict__ srcw) {
    int* hist = (int*)smem;          // 256
    int* sc   = hist + 256;          // 256
    int* cur  = sc + 256;            // 256
    int* red  = cur + 256;           // 4
    int* s_base = red + 4;           // 1
    int tid = threadIdx.x;
    hist[tid] = 0;

    int partial = 0;
    for (int i = tid; i < b * NSEG; i += 256) {
        int bp = i >> 5, s = i & 31;
        int c = cnt[s * NB + bp];
        partial += (c < CAP ? c : CAP);
    }
    int onum = *ocnt; if (onum > OCAP) onum = OCAP;
    for (int i = tid; i < onum; i += 256)
        if ((odst[i] >> BSH) < b) ++partial;
    #pragma unroll
    for (int off = 32; off; off >>= 1) partial += __shfl_xor(partial, off);
    if ((tid & 63) == 0) red[tid >> 6] = partial;
    __syncthreads();
    if (tid == 0) *s_base = red[0] + red[1] + red[2] + red[3];
    __syncthreads();

    for (int s = 0; s < NSEG; ++s) {
        int c = cnt[s * NB + b]; if (c > CAP) c = CAP;
        const int2* rp = &rec[(size_t)(s * NB + b) * CAP];
        for (int i = tid; i < c; i += 256)
            atomicAdd(&hist[(rp[i].x >> 17) & 255], 1);
    }
    for (int i = tid; i < onum; i += 256) {
        int d = odst[i];
        if ((d >> BSH) == b) atomicAdd(&hist[d & 255], 1);
    }
    __syncthreads();

    sc[tid] = hist[tid];
    __syncthreads();
    for (int off = 1; off < 256; off <<= 1) {
        int v = (tid >= off) ? sc[tid - off] : 0;
        __syncthreads();
        sc[tid] += v;
        __syncthreads();
    }
    int excl = (tid > 0) ? sc[tid - 1] : 0;
    cur[tid] = excl;
    int base = *s_base;
    int node = b * 256 + tid;
    if (node <= N_NODES) rowptr[node] = base + excl;
    __syncthreads();

    for (int s = 0; s < NSEG; ++s) {
        int c = cnt[s * NB + b]; if (c > CAP) c = CAP;
        const int2* rp = &rec[(size_t)(s * NB + b) * CAP];
        for (int i = tid; i < c; i += 256) {
            int2 r = rp[i];
            int dl = (r.x >> 17) & 255;
            int p = atomicAdd(&cur[dl], 1);
            srcw[base + p] = make_int2(r.x & 0x1FFFF, r.y);
        }
    }
    for (int i = tid; i < onum; i += 256) {
        int d = odst[i];
        if ((d >> BSH) == b) {
            int p = atomicAdd(&cur[d & 255], 1);
            srcw[base + p] = osw[i];
        }
    }
}

// ---------------------------------------------------------------------------
// gemm1 body (MFMA bf16): h[100000,128]fp16 = x @ W1. 128x128 tile, 4 waves.
// ---------------------------------------------------------------------------
static __device__ void gemm1_body(char* smem, int bid, const float* __restrict__ x,
                                  const short* __restrict__ w1t,
                                  __half* __restrict__ h) {
    int tid = threadIdx.x;
    int lane = tid & 63, wid = tid >> 6;
    int wr = wid >> 1, wc = wid & 1;
    int m0 = bid * 128;
    f32x4 acc[4][4] = {{{0.f}}};
    for (int kb = 0; kb < 256; kb += 64) {
        #pragma unroll
        for (int t = 0; t < 8; ++t) {
            int id = tid + t * 256;
            int row = id >> 4, c4 = id & 15;
            int gr = m0 + row; if (gr >= N_NODES) gr = N_NODES - 1;
            float4 g = *(const float4*)&x[(size_t)gr * F_INF + kb + c4 * 4];
            short4 s4 = { bf16c(g.x), bf16c(g.y), bf16c(g.z), bf16c(g.w) };
            int byte = row * 128 + c4 * 8;
            byte ^= (row & 7) << 4;
            *(short4*)(smem + byte) = s4;
        }
        __syncthreads();
        #pragma unroll
        for (int km = 0; km < 2; ++km) {
            bf16x8 af[4], bfr[4];
            #pragma unroll
            for (int mi = 0; mi < 4; ++mi) {
                int row = wr * 64 + mi * 16 + (lane & 15);
                int kk = km * 32 + (lane >> 4) * 8;
                int byte = row * 128 + kk * 2;
                byte ^= (row & 7) << 4;
                af[mi] = *(bf16x8*)(smem + byte);
            }
            #pragma unroll
            for (int ni = 0; ni < 4; ++ni) {
                int col = wc * 64 + ni * 16 + (lane & 15);
                int kk = kb + km * 32 + (lane >> 4) * 8;
                bfr[ni] = *(const bf16x8*)&w1t[col * 256 + kk];
            }
            #pragma unroll
            for (int mi = 0; mi < 4; ++mi)
                #pragma unroll
                for (int ni = 0; ni < 4; ++ni)
                    acc[mi][ni] = __builtin_amdgcn_mfma_f32_16x16x32_bf16(
                        af[mi], bfr[ni], acc[mi][ni], 0, 0, 0);
        }
        __syncthreads();
    }
    #pragma unroll
    for (int mi = 0; mi < 4; ++mi) {
        int rbase = m0 + wr * 64 + mi * 16 + ((lane >> 4) << 2);
        #pragma unroll
        for (int ni = 0; ni < 4; ++ni) {
            int col = wc * 64 + ni * 16 + (lane & 15);
            #pragma unroll
            for (int r = 0; r < 4; ++r) {
                int row = rbase + r;
                if (row < N_NODES)
                    h[(size_t)row * HIDF + col] = __float2half(acc[mi][ni][r]);
            }
        }
    }
}

__global__ __launch_bounds__(256) void csr_gemm1_kernel(const int* __restrict__ cnt,
        const int2* __restrict__ rec, const int* __restrict__ ocnt,
        const int2* __restrict__ osw, const int* __restrict__ odst,
        int* __restrict__ rowptr, int2* __restrict__ srcw,
        const float* __restrict__ x, const short* __restrict__ w1t,
        __half* __restrict__ h) {
    __shared__ char smem[16384];
    if (blockIdx.x < NB)
        csr_body(smem, blockIdx.x, cnt, rec, ocnt, osw, odst, rowptr, srcw);
    else
        gemm1_body(smem, blockIdx.x - NB, x, w1t, h);
}

// ---------------------------------------------------------------------------
// agg1: per-node wave CSR gather, 4 edges x 16 uint4-chunks, depth 4
// (16 edges / 4 loads in flight per lane) + srcw window prefetch.
// fused +b1 + relu, fp16 out.
// ---------------------------------------------------------------------------
__global__ __launch_bounds__(256) void agg1_kernel(const __half* __restrict__ h,
                                                   const int2* __restrict__ srcw,
                                                   const int* __restrict__ rowptr,
                                                   const float* __restrict__ b1,
                                                   __half* __restrict__ hact) {
    int lane = threadIdx.x & 63;
    int node = blockIdx.x * 4 + (threadIdx.x >> 6);
    if (node >= N_NODES) return;
    int beg = rowptr[node], end = rowptr[node + 1];
    int eo = lane >> 4, fo = lane & 15;          // 4 edges x 16 chunks(8 halfs)
    float4 a0 = {0.f, 0.f, 0.f, 0.f}, a1 = {0.f, 0.f, 0.f, 0.f};
    const uint4* hp = (const uint4*)h;           // row = 16 x uint4
    int idx0 = beg + lane;
    int2 sw = srcw[idx0 < end ? idx0 : end - 1];
    for (int base = beg; base < end; base += 64) {
        int cnt = end - base; if (cnt > 64) cnt = 64;
        int nidx = base + 64 + lane;
        int2 swn = srcw[nidx < end ? nidx : end - 1];   // prefetch next window
        for (int j = 0; j < cnt; j += 16) {
            int s[4]; float w[4];
            #pragma unroll
            for (int u = 0; u < 4; ++u) {
                int jj = j + u * 4 + eo;
                s[u] = __shfl(sw.x, jj);
                w[u] = __int_as_float(__shfl(sw.y, jj));
                if (jj >= cnt) w[u] = 0.f;
            }
            uint4 hv[4];
            #pragma unroll
            for (int u = 0; u < 4; ++u) hv[u] = hp[(size_t)s[u] * 16 + fo];
            #pragma unroll
            for (int u = 0; u < 4; ++u) {
                const __half2* p = (const __half2*)&hv[u];
                float2 f;
                f = __half22float2(p[0]); a0.x += w[u] * f.x; a0.y += w[u] * f.y;
                f = __half22float2(p[1]); a0.z += w[u] * f.x; a0.w += w[u] * f.y;
                f = __half22float2(p[2]); a1.x += w[u] * f.x; a1.y += w[u] * f.y;
                f = __half22float2(p[3]); a1.z += w[u] * f.x; a1.w += w[u] * f.y;
            }
        }
        sw = swn;
    }
    #pragma unroll
    for (int off = 16; off < 64; off <<= 1) {
        a0.x += __shfl_xor(a0.x, off); a0.y += __shfl_xor(a0.y, off);
        a0.z += __shfl_xor(a0.z, off); a0.w += __shfl_xor(a0.w, off);
        a1.x += __shfl_xor(a1.x, off); a1.y += __shfl_xor(a1.y, off);
        a1.z += __shfl_xor(a1.z, off); a1.w += __shfl_xor(a1.w, off);
    }
    if (lane < 16) {
        float4 bb0 = *(const float4*)&b1[fo * 8];
        float4 bb1 = *(const float4*)&b1[fo * 8 + 4];
        __half2 o0 = __floats2half2_rn(fmaxf(a0.x + bb0.x, 0.f), fmaxf(a0.y + bb0.y, 0.f));
        __half2 o1 = __floats2half2_rn(fmaxf(a0.z + bb0.z, 0.f), fmaxf(a0.w + bb0.w, 0.f));
        __half2 o2 = __floats2half2_rn(fmaxf(a1.x + bb1.x, 0.f), fmaxf(a1.y + bb1.y, 0.f));
        __half2 o3 = __floats2half2_rn(fmaxf(a1.z + bb1.z, 0.f), fmaxf(a1.w + bb1.w, 0.f));
        uint4 ov = { *(uint*)&o0, *(uint*)&o1, *(uint*)&o2, *(uint*)&o3 };
        ((uint4*)hact)[(size_t)node * 16 + fo] = ov;
    }
}

// ---------------------------------------------------------------------------
// GEMM2: h2p[100000,64]fp16(padded 40) = hact[100000,128]fp16 @ W2[128,40]
// ---------------------------------------------------------------------------
__global__ __launch_bounds__(320) void gemm2_kernel(const __half* __restrict__ hact,
                                                    const float* __restrict__ W2,
                                                    __half* __restrict__ h2p) {
    __shared__ float xT[128 * 68];   // [k][row]
    __shared__ float w2[128 * 40];
    int tid = threadIdx.x;
    int tx = tid % 40, ty = tid / 40;
    int m0 = blockIdx.x * 64;
    for (int i = tid; i < 128 * 40; i += 320) w2[i] = W2[i];
    for (int i = tid; i < 1024; i += 320) {
        int row = i >> 4, c8 = i & 15;
        int gr = m0 + row; if (gr >= N_NODES) gr = N_NODES - 1;
        uint4 v = *(const uint4*)&hact[(size_t)gr * HIDF + c8 * 8];
        const __half2* ph = (const __half2*)&v;
        #pragma unroll
        for (int t = 0; t < 4; ++t) {
            float2 f = __half22float2(ph[t]);
            int k = c8 * 8 + t * 2;
            xT[(k + 0) * 68 + row] = f.x;
            xT[(k + 1) * 68 + row] = f.y;
        }
    }
    // zero the pad columns (40..63) for this block's 64 rows
    for (int i = tid; i < 64 * 3; i += 320) {
        int row = i / 3, c = i % 3;
        int gr = m0 + row;
        if (gr < N_NODES) {
            uint4 z = {0, 0, 0, 0};
            *(uint4*)&h2p[(size_t)gr * H2P + 40 + c * 8] = z;
        }
    }
    __syncthreads();
    float acc[8] = {};
    #pragma unroll 4
    for (int k = 0; k < 128; ++k) {
        float wv = w2[k * 40 + tx];
        float4 xa = *(float4*)&xT[k * 68 + ty * 8];
        float4 xb = *(float4*)&xT[k * 68 + ty * 8 + 4];
        acc[0] += xa.x * wv; acc[1] += xa.y * wv;
        acc[2] += xa.z * wv; acc[3] += xa.w * wv;
        acc[4] += xb.x * wv; acc[5] += xb.y * wv;
        acc[6] += xb.z * wv; acc[7] += xb.w * wv;
    }
    #pragma unroll
    for (int i = 0; i < 8; ++i) {
        int r = m0 + ty * 8 + i;
        if (r < N_NODES) h2p[(size_t)r * H2P + tx] = __float2half(acc[i]);
    }
}

// ---------------------------------------------------------------------------
// agg2: per-node wave CSR gather on padded h2p rows (8 uint4 = 128B),
// 8 edges x 8 chunks, depth 2 (16 edges in flight) + srcw prefetch.
// fused +b2 + log_softmax (40 classes), f32 out.
// ---------------------------------------------------------------------------
__global__ __launch_bounds__(256) void agg2_kernel(const __half* __restrict__ h2p,
                                                   const int2* __restrict__ srcw,
                                                   const int* __restrict__ rowptr,
                                                   const float* __restrict__ b2,
                                                   float* __restrict__ out) {
    int lane = threadIdx.x & 63;
    int node = blockIdx.x * 4 + (threadIdx.x >> 6);
    if (node >= N_NODES) return;
    int beg = rowptr[node], end = rowptr[node + 1];
    int eo = lane >> 3, fo = lane & 7;           // 8 edges x 8 chunks(8 halfs)
    float4 a0 = {0.f, 0.f, 0.f, 0.f}, a1 = {0.f, 0.f, 0.f, 0.f};
    const uint4* hp = (const uint4*)h2p;         // row = 8 x uint4
    int idx0 = beg + lane;
    int2 sw = srcw[idx0 < end ? idx0 : end - 1];
    for (int base = beg; base < end; base += 64) {
        int cnt = end - base; if (cnt > 64) cnt = 64;
        int nidx = base + 64 + lane;
        int2 swn = srcw[nidx < end ? nidx : end - 1];
        for (int j = 0; j < cnt; j += 16) {
            int s[2]; float w[2];
            #pragma unroll
            for (int u = 0; u < 2; ++u) {
                int jj = j + u * 8 + eo;
                s[u] = __shfl(sw.x, jj);
                w[u] = __int_as_float(__shfl(sw.y, jj));
                if (jj >= cnt) w[u] = 0.f;
            }
            uint4 hv[2];
            #pragma unroll
            for (int u = 0; u < 2; ++u) hv[u] = hp[(size_t)s[u] * 8 + fo];
            #pragma unroll
            for (int u = 0; u < 2; ++u) {
                const __half2* p = (const __half2*)&hv[u];
                float2 f;
                f = __half22float2(p[0]); a0.x += w[u] * f.x; a0.y += w[u] * f.y;
                f = __half22float2(p[1]); a0.z += w[u] * f.x; a0.w += w[u] * f.y;
                f = __half22float2(p[2]); a1.x += w[u] * f.x; a1.y += w[u] * f.y;
                f = __half22float2(p[3]); a1.z += w[u] * f.x; a1.w += w[u] * f.y;
            }
        }
        sw = swn;
    }
    #pragma unroll
    for (int off = 8; off < 64; off <<= 1) {
        a0.x += __shfl_xor(a0.x, off); a0.y += __shfl_xor(a0.y, off);
        a0.z += __shfl_xor(a0.z, off); a0.w += __shfl_xor(a0.w, off);
        a1.x += __shfl_xor(a1.x, off); a1.y += __shfl_xor(a1.y, off);
        a1.z += __shfl_xor(a1.z, off); a1.w += __shfl_xor(a1.w, off);
    }
    // lanes 0..7 hold chunk fo (feats fo*8..fo*8+7); fo<5 are real classes
    float v[8];
    bool act = (lane < 8) && (fo < 5);
    #pragma unroll
    for (int t = 0; t < 8; ++t) v[t] = -INFINITY;
    if (act) {
        float4 bb0 = *(const float4*)&b2[fo * 8];
        float4 bb1 = *(const float4*)&b2[fo * 8 + 4];
        v[0] = a0.x + bb0.x; v[1] = a0.y + bb0.y;
        v[2] = a0.z + bb0.z; v[3] = a0.w + bb0.w;
        v[4] = a1.x + bb1.x; v[5] = a1.y + bb1.y;
        v[6] = a1.z + bb1.z; v[7] = a1.w + bb1.w;
    }
    float m = v[0];
    #pragma unroll
    for (int t = 1; t < 8; ++t) m = fmaxf(m, v[t]);
    #pragma unroll
    for (int off = 1; off < 8; off <<= 1) m = fmaxf(m, __shfl_xor(m, off));
    float ex = 0.f;
    if (act) {
        #pragma unroll
        for (int t = 0; t < 8; ++t) ex += expf(v[t] - m);
    }
    #pragma unroll
    for (int off = 1; off < 8; off <<= 1) ex += __shfl_xor(ex, off);
    float ls = logf(ex);
    if (act) {
        float4 o0 = { v[0]-m-ls, v[1]-m-ls, v[2]-m-ls, v[3]-m-ls };
        float4 o1 = { v[4]-m-ls, v[5]-m-ls, v[6]-m-ls, v[7]-m-ls };
        *(float4*)&out[(size_t)node * C_OUT + fo * 8] = o0;
        *(float4*)&out[(size_t)node * C_OUT + fo * 8 + 4] = o1;
    }
}

// ---------------------------------------------------------------------------

extern "C" void kernel_launch(void* const* d_in, const int* in_sizes, int n_in,
                              void* d_out, int out_size, void* d_ws, size_t ws_size,
                              hipStream_t stream) {
    const float* x  = (const float*)d_in[0];
    const int*   ei = (const int*)d_in[1];      // [2,E]: row0=src, row1=dst
    const float* ew = (const float*)d_in[2];
    const float* W1 = (const float*)d_in[3];
    const float* b1 = (const float*)d_in[4];
    const float* W2 = (const float*)d_in[5];
    const float* b2 = (const float*)d_in[6];
    float* out = (float*)d_out;

    char* ws = (char*)d_ws;
    size_t off = 0;
    auto alloc = [&](size_t bytes) -> void* {
        void* p = ws + off;
        off += (bytes + 255) & ~(size_t)255;
        return p;
    };
    __half* h      = (__half*)alloc((size_t)N_NODES * HIDF * 2);     // 25.6 MB
    __half* hact   = (__half*)alloc((size_t)N_NODES * HIDF * 2);     // 25.6 MB
    __half* h2p    = (__half*)alloc((size_t)N_NODES * H2P * 2);      // 12.8 MB
    short*  w1t    = (short*)alloc((size_t)HIDF * F_INF * 2);        // 64 KB
    int*    rowptr = (int*)alloc((size_t)(N_NODES + 1) * 4);
    int2*   srcw   = (int2*)alloc((size_t)E_EDGES * 8);              // 25.6 MB
    int2*   rec    = (int2*)alloc((size_t)NSEG * NB * CAP * 8);      // 38.4 MB
    int*    cnt    = (int*)alloc((size_t)NSEG * NB * 4);             // 50 KB
    int*    ocnt   = (int*)alloc(256);
    int2*   osw    = (int2*)alloc((size_t)OCAP * 8);                 // 2 MB
    int*    odst   = (int*)alloc((size_t)OCAP * 4);                  // 1 MB

    hipMemsetAsync(cnt, 0, (size_t)NSEG * NB * 4, stream);
    hipMemsetAsync(ocnt, 0, 4, stream);

    scat_w1t_kernel<<<SCAT_BLOCKS + W1T_BLOCKS, 256, 0, stream>>>(
        ei, ew, cnt, rec, ocnt, osw, odst, W1, w1t);
    csr_gemm1_kernel<<<NB + GEMM1_BLOCKS, 256, 0, stream>>>(
        cnt, rec, ocnt, osw, odst, rowptr, srcw, x, w1t, h);
    agg1_kernel<<<(N_NODES + 3) / 4, 256, 0, stream>>>(h, srcw, rowptr, b1, hact);
    gemm2_kernel<<<(N_NODES + 63) / 64, 320, 0, stream>>>(hact, W2, h2p);
    agg2_kernel<<<(N_NODES + 3) / 4, 256, 0, stream>>>(h2p, srcw, rowptr, b2, out);
}

// Round 6
// 484.494 us; speedup vs baseline: 2.1273x; 1.1320x over previous
//
#include <hip/hip_runtime.h>
#include <hip/hip_bf16.h>
#include <hip/hip_fp16.h>
#include <math.h>

#define N_NODES 100000
#define E_EDGES 3200000
#define F_INF   256
#define HIDF    128
#define C_OUT   40
#define H2P     64         // padded h2 row (fp16)

// bucketed CSR build params
#define BSH   8            // bucket = dst >> 8 (256 nodes per bucket)
#define NB    391          // ceil(100000/256)
#define NSEG  8            // per-XCD sub-streams
#define CAPX  1280         // per (seg,bucket) capacity; mean 1023, +8 sigma
#define OCAP  262144       // overflow list capacity
#define EPB   1563         // edges per block in scat (2048 blocks)
#define BUFSZ 1568
#define SCAT_BLOCKS 2048
#define W1T_BLOCKS  128
#define GEMM1_BLOCKS ((N_NODES + 127) / 128)
#define SCAT_LDS    26112

typedef __attribute__((ext_vector_type(8))) short bf16x8;
typedef __attribute__((ext_vector_type(4))) float f32x4;

static __device__ __forceinline__ short bf16c(float f) {
    __hip_bfloat16 b = __float2bfloat16(f);
    return *reinterpret_cast<short*>(&b);
}

// ---------------------------------------------------------------------------
// scat body: block-local LDS counting sort of 1563 edges -> coalesced
// segment flush into per-(seg,bucket) streams. One global atomic per
// (block,bucket) instead of per edge; ~1x write amplification.
// ---------------------------------------------------------------------------
static __device__ void scat_body(char* smem, int bid, const int* __restrict__ ei,
        const float* __restrict__ ew, int* __restrict__ cnt,
        int2* __restrict__ rec, int* __restrict__ ocnt,
        int2* __restrict__ osw, int* __restrict__ odst) {
    int* hist  = (int*)smem;           // 392
    int* g     = hist + 392;           // 256
    int* lcur  = g + 256;              // 392: exclusive base, then cursor
    int* gsA   = lcur + 392;           // 392
    int* lim   = gsA + 392;            // 392
    int2* buf  = (int2*)(lim + 392);   // 1568 records
    int* gdest = (int*)(buf + BUFSZ);  // 1568
    int tid = threadIdx.x;
    int seg = bid & (NSEG - 1);
    int e0 = bid * EPB;
    int e1 = e0 + EPB; if (e1 > E_EDGES) e1 = E_EDGES;
    int tot = e1 - e0;

    for (int i = tid; i < 392; i += 256) hist[i] = 0;
    __syncthreads();

    // load edges to registers + LDS histogram
    int pk[7]; float wv[7]; int bk[7]; int nr = 0;
    #pragma unroll
    for (int r = 0; r < 7; ++r) {
        int e = e0 + r * 256 + tid;
        if (e < e1) {
            int dst = __builtin_nontemporal_load(&ei[E_EDGES + e]);
            int src = __builtin_nontemporal_load(&ei[e]);
            float w = __builtin_nontemporal_load(&ew[e]);
            int b = dst >> BSH;
            pk[nr] = src | ((dst & 255) << 17);
            wv[nr] = w; bk[nr] = b; ++nr;
            atomicAdd(&hist[b], 1);
        }
    }
    __syncthreads();

    // pair-scan: 392 buckets -> 196 pairs -> Hillis-Steele over 256
    int h0 = (2 * tid < 392) ? hist[2 * tid] : 0;
    int h1 = (2 * tid + 1 < 392) ? hist[2 * tid + 1] : 0;
    g[tid] = h0 + h1;
    __syncthreads();
    for (int off = 1; off < 256; off <<= 1) {
        int v = (tid >= off) ? g[tid - off] : 0;
        __syncthreads();
        g[tid] += v;
        __syncthreads();
    }
    int pg = (tid > 0) ? g[tid - 1] : 0;
    if (2 * tid < 392)     lcur[2 * tid] = pg;
    if (2 * tid + 1 < 392) lcur[2 * tid + 1] = pg + h0;
    __syncthreads();

    // reserve global stream space: one atomic per touched bucket
    for (int b = tid; b < NB; b += 256) {
        int c = hist[b];
        int gb = 0;
        if (c > 0) gb = atomicAdd(&cnt[seg * NB + b], c);
        int lb = lcur[b];
        gsA[b] = (seg * NB + b) * CAPX + gb - lb;
        lim[b] = lb + (CAPX - gb);      // p < lim  =>  within capacity
    }
    __syncthreads();

    // scatter into sorted LDS buffer
    for (int r = 0; r < nr; ++r) {
        int b = bk[r];
        int p = atomicAdd(&lcur[b], 1);
        buf[p] = make_int2(pk[r], __float_as_int(wv[r]));
        gdest[p] = (p < lim[b]) ? (gsA[b] + p) : -(b + 1);
    }
    __syncthreads();

    // coalesced flush
    for (int i = tid; i < tot; i += 256) {
        int d = gdest[i];
        int2 rr = buf[i];
        if (d >= 0) {
            rec[d] = rr;
        } else {
            int b = -d - 1;
            int dst = (b << 8) | ((rr.x >> 17) & 255);
            int op = atomicAdd(ocnt, 1);
            if (op < OCAP) { osw[op] = make_int2(rr.x & 0x1FFFF, rr.y); odst[op] = dst; }
        }
    }
}

static __device__ void w1t_body(int bid, const float* __restrict__ W1,
                                short* __restrict__ w1t) {
    int idx = bid * 256 + threadIdx.x;  // 0..32767
    int k = idx >> 7, c = idx & 127;
    w1t[c * 256 + k] = bf16c(W1[idx]);
}

__global__ __launch_bounds__(256) void scat_w1t_kernel(const int* __restrict__ ei,
        const float* __restrict__ ew, int* __restrict__ cnt,
        int2* __restrict__ rec, int* __restrict__ ocnt,
        int2* __restrict__ osw, int* __restrict__ odst,
        const float* __restrict__ W1, short* __restrict__ w1t) {
    __shared__ char smem[SCAT_LDS];
    if (blockIdx.x < SCAT_BLOCKS)
        scat_body(smem, blockIdx.x, ei, ew, cnt, rec, ocnt, osw, odst);
    else
        w1t_body(blockIdx.x - SCAT_BLOCKS, W1, w1t);
}

// ---------------------------------------------------------------------------
// csr body: one block per bucket -> rowptr + final CSR scatter (L2-resident)
// ---------------------------------------------------------------------------
static __device__ void csr_body(char* smem, int b, const int* __restrict__ cnt,
        const int2* __restrict__ rec, const int* __restrict__ ocnt,
        const int2* __restrict__ osw, const int* __restrict__ odst,
        int* __restrict__ rowptr, int2* __restrict__ srcw) {
    int* hist = (int*)smem;          // 256
    int* sc   = hist + 256;          // 256
    int* cur  = sc + 256;            // 256
    int* red  = cur + 256;           // 4
    int* s_base = red + 4;           // 1
    int tid = threadIdx.x;
    hist[tid] = 0;

    int partial = 0;
    for (int i = tid; i < b * NSEG; i += 256) {
        int bp = i >> 3, s = i & 7;
        int c = cnt[s * NB + bp];
        partial += (c < CAPX ? c : CAPX);
    }
    int onum = *ocnt; if (onum > OCAP) onum = OCAP;
    for (int i = tid; i < onum; i += 256)
        if ((odst[i] >> BSH) < b) ++partial;
    #pragma unroll
    for (int off = 32; off; off >>= 1) partial += __shfl_xor(partial, off);
    if ((tid & 63) == 0) red[tid >> 6] = partial;
    __syncthreads();
    if (tid == 0) *s_base = red[0] + red[1] + red[2] + red[3];
    __syncthreads();

    for (int s = 0; s < NSEG; ++s) {
        int c = cnt[s * NB + b]; if (c > CAPX) c = CAPX;
        const int2* rp = &rec[(size_t)(s * NB + b) * CAPX];
        for (int i = tid; i < c; i += 256)
            atomicAdd(&hist[(rp[i].x >> 17) & 255], 1);
    }
    for (int i = tid; i < onum; i += 256) {
        int d = odst[i];
        if ((d >> BSH) == b) atomicAdd(&hist[d & 255], 1);
    }
    __syncthreads();

    sc[tid] = hist[tid];
    __syncthreads();
    for (int off = 1; off < 256; off <<= 1) {
        int v = (tid >= off) ? sc[tid - off] : 0;
        __syncthreads();
        sc[tid] += v;
        __syncthreads();
    }
    int excl = (tid > 0) ? sc[tid - 1] : 0;
    cur[tid] = excl;
    int base = *s_base;
    int node = b * 256 + tid;
    if (node <= N_NODES) rowptr[node] = base + excl;
    __syncthreads();

    for (int s = 0; s < NSEG; ++s) {
        int c = cnt[s * NB + b]; if (c > CAPX) c = CAPX;
        const int2* rp = &rec[(size_t)(s * NB + b) * CAPX];
        for (int i = tid; i < c; i += 256) {
            int2 r = rp[i];
            int dl = (r.x >> 17) & 255;
            int p = atomicAdd(&cur[dl], 1);
            srcw[base + p] = make_int2(r.x & 0x1FFFF, r.y);
        }
    }
    for (int i = tid; i < onum; i += 256) {
        int d = odst[i];
        if ((d >> BSH) == b) {
            int p = atomicAdd(&cur[d & 255], 1);
            srcw[base + p] = osw[i];
        }
    }
}

// ---------------------------------------------------------------------------
// gemm1 body (MFMA bf16): h[100000,128]fp16 = x @ W1. 128x128 tile, 4 waves.
// ---------------------------------------------------------------------------
static __device__ void gemm1_body(char* smem, int bid, const float* __restrict__ x,
                                  const short* __restrict__ w1t,
                                  __half* __restrict__ h) {
    int tid = threadIdx.x;
    int lane = tid & 63, wid = tid >> 6;
    int wr = wid >> 1, wc = wid & 1;
    int m0 = bid * 128;
    f32x4 acc[4][4] = {{{0.f}}};
    for (int kb = 0; kb < 256; kb += 64) {
        #pragma unroll
        for (int t = 0; t < 8; ++t) {
            int id = tid + t * 256;
            int row = id >> 4, c4 = id & 15;
            int gr = m0 + row; if (gr >= N_NODES) gr = N_NODES - 1;
            float4 g = *(const float4*)&x[(size_t)gr * F_INF + kb + c4 * 4];
            short4 s4 = { bf16c(g.x), bf16c(g.y), bf16c(g.z), bf16c(g.w) };
            int byte = row * 128 + c4 * 8;
            byte ^= (row & 7) << 4;
            *(short4*)(smem + byte) = s4;
        }
        __syncthreads();
        #pragma unroll
        for (int km = 0; km < 2; ++km) {
            bf16x8 af[4], bfr[4];
            #pragma unroll
            for (int mi = 0; mi < 4; ++mi) {
                int row = wr * 64 + mi * 16 + (lane & 15);
                int kk = km * 32 + (lane >> 4) * 8;
                int byte = row * 128 + kk * 2;
                byte ^= (row & 7) << 4;
                af[mi] = *(bf16x8*)(smem + byte);
            }
            #pragma unroll
            for (int ni = 0; ni < 4; ++ni) {
                int col = wc * 64 + ni * 16 + (lane & 15);
                int kk = kb + km * 32 + (lane >> 4) * 8;
                bfr[ni] = *(const bf16x8*)&w1t[col * 256 + kk];
            }
            #pragma unroll
            for (int mi = 0; mi < 4; ++mi)
                #pragma unroll
                for (int ni = 0; ni < 4; ++ni)
                    acc[mi][ni] = __builtin_amdgcn_mfma_f32_16x16x32_bf16(
                        af[mi], bfr[ni], acc[mi][ni], 0, 0, 0);
        }
        __syncthreads();
    }
    #pragma unroll
    for (int mi = 0; mi < 4; ++mi) {
        int rbase = m0 + wr * 64 + mi * 16 + ((lane >> 4) << 2);
        #pragma unroll
        for (int ni = 0; ni < 4; ++ni) {
            int col = wc * 64 + ni * 16 + (lane & 15);
            #pragma unroll
            for (int r = 0; r < 4; ++r) {
                int row = rbase + r;
                if (row < N_NODES)
                    h[(size_t)row * HIDF + col] = __float2half(acc[mi][ni][r]);
            }
        }
    }
}

__global__ __launch_bounds__(256) void csr_gemm1_kernel(const int* __restrict__ cnt,
        const int2* __restrict__ rec, const int* __restrict__ ocnt,
        const int2* __restrict__ osw, const int* __restrict__ odst,
        int* __restrict__ rowptr, int2* __restrict__ srcw,
        const float* __restrict__ x, const short* __restrict__ w1t,
        __half* __restrict__ h) {
    __shared__ char smem[16384];
    if (blockIdx.x < NB)
        csr_body(smem, blockIdx.x, cnt, rec, ocnt, osw, odst, rowptr, srcw);
    else
        gemm1_body(smem, blockIdx.x - NB, x, w1t, h);
}

// ---------------------------------------------------------------------------
// agg1: per-node wave CSR gather, 4 edges x 16 uint4-chunks, depth 4
// (16 edges / 4 loads in flight per lane) + srcw window prefetch.
// fused +b1 + relu, fp16 out.
// ---------------------------------------------------------------------------
__global__ __launch_bounds__(256) void agg1_kernel(const __half* __restrict__ h,
                                                   const int2* __restrict__ srcw,
                                                   const int* __restrict__ rowptr,
                                                   const float* __restrict__ b1,
                                                   __half* __restrict__ hact) {
    int lane = threadIdx.x & 63;
    int node = blockIdx.x * 4 + (threadIdx.x >> 6);
    if (node >= N_NODES) return;
    int beg = rowptr[node], end = rowptr[node + 1];
    int eo = lane >> 4, fo = lane & 15;          // 4 edges x 16 chunks(8 halfs)
    float4 a0 = {0.f, 0.f, 0.f, 0.f}, a1 = {0.f, 0.f, 0.f, 0.f};
    const uint4* hp = (const uint4*)h;           // row = 16 x uint4
    int idx0 = beg + lane;
    int2 sw = srcw[idx0 < end ? idx0 : end - 1];
    for (int base = beg; base < end; base += 64) {
        int cnt = end - base; if (cnt > 64) cnt = 64;
        int nidx = base + 64 + lane;
        int2 swn = srcw[nidx < end ? nidx : end - 1];   // prefetch next window
        for (int j = 0; j < cnt; j += 16) {
            int s[4]; float w[4];
            #pragma unroll
            for (int u = 0; u < 4; ++u) {
                int jj = j + u * 4 + eo;
                s[u] = __shfl(sw.x, jj);
                w[u] = __int_as_float(__shfl(sw.y, jj));
                if (jj >= cnt) w[u] = 0.f;
            }
            uint4 hv[4];
            #pragma unroll
            for (int u = 0; u < 4; ++u) hv[u] = hp[(size_t)s[u] * 16 + fo];
            #pragma unroll
            for (int u = 0; u < 4; ++u) {
                const __half2* p = (const __half2*)&hv[u];
                float2 f;
                f = __half22float2(p[0]); a0.x += w[u] * f.x; a0.y += w[u] * f.y;
                f = __half22float2(p[1]); a0.z += w[u] * f.x; a0.w += w[u] * f.y;
                f = __half22float2(p[2]); a1.x += w[u] * f.x; a1.y += w[u] * f.y;
                f = __half22float2(p[3]); a1.z += w[u] * f.x; a1.w += w[u] * f.y;
            }
        }
        sw = swn;
    }
    #pragma unroll
    for (int off = 16; off < 64; off <<= 1) {
        a0.x += __shfl_xor(a0.x, off); a0.y += __shfl_xor(a0.y, off);
        a0.z += __shfl_xor(a0.z, off); a0.w += __shfl_xor(a0.w, off);
        a1.x += __shfl_xor(a1.x, off); a1.y += __shfl_xor(a1.y, off);
        a1.z += __shfl_xor(a1.z, off); a1.w += __shfl_xor(a1.w, off);
    }
    if (lane < 16) {
        float4 bb0 = *(const float4*)&b1[fo * 8];
        float4 bb1 = *(const float4*)&b1[fo * 8 + 4];
        __half2 o0 = __floats2half2_rn(fmaxf(a0.x + bb0.x, 0.f), fmaxf(a0.y + bb0.y, 0.f));
        __half2 o1 = __floats2half2_rn(fmaxf(a0.z + bb0.z, 0.f), fmaxf(a0.w + bb0.w, 0.f));
        __half2 o2 = __floats2half2_rn(fmaxf(a1.x + bb1.x, 0.f), fmaxf(a1.y + bb1.y, 0.f));
        __half2 o3 = __floats2half2_rn(fmaxf(a1.z + bb1.z, 0.f), fmaxf(a1.w + bb1.w, 0.f));
        uint4 ov = { *(uint*)&o0, *(uint*)&o1, *(uint*)&o2, *(uint*)&o3 };
        ((uint4*)hact)[(size_t)node * 16 + fo] = ov;
    }
}

// ---------------------------------------------------------------------------
// GEMM2: h2p[100000,64]fp16(padded 40) = hact[100000,128]fp16 @ W2[128,40]
// ---------------------------------------------------------------------------
__global__ __launch_bounds__(320) void gemm2_kernel(const __half* __restrict__ hact,
                                                    const float* __restrict__ W2,
                                                    __half* __restrict__ h2p) {
    __shared__ float xT[128 * 68];   // [k][row]
    __shared__ float w2[128 * 40];
    int tid = threadIdx.x;
    int tx = tid % 40, ty = tid / 40;
    int m0 = blockIdx.x * 64;
    for (int i = tid; i < 128 * 40; i += 320) w2[i] = W2[i];
    for (int i = tid; i < 1024; i += 320) {
        int row = i >> 4, c8 = i & 15;
        int gr = m0 + row; if (gr >= N_NODES) gr = N_NODES - 1;
        uint4 v = *(const uint4*)&hact[(size_t)gr * HIDF + c8 * 8];
        const __half2* ph = (const __half2*)&v;
        #pragma unroll
        for (int t = 0; t < 4; ++t) {
            float2 f = __half22float2(ph[t]);
            int k = c8 * 8 + t * 2;
            xT[(k + 0) * 68 + row] = f.x;
            xT[(k + 1) * 68 + row] = f.y;
        }
    }
    // zero the pad columns (40..63) for this block's 64 rows
    for (int i = tid; i < 64 * 3; i += 320) {
        int row = i / 3, c = i % 3;
        int gr = m0 + row;
        if (gr < N_NODES) {
            uint4 z = {0, 0, 0, 0};
            *(uint4*)&h2p[(size_t)gr * H2P + 40 + c * 8] = z;
        }
    }
    __syncthreads();
    float acc[8] = {};
    #pragma unroll 4
    for (int k = 0; k < 128; ++k) {
        float wv = w2[k * 40 + tx];
        float4 xa = *(float4*)&xT[k * 68 + ty * 8];
        float4 xb = *(float4*)&xT[k * 68 + ty * 8 + 4];
        acc[0] += xa.x * wv; acc[1] += xa.y * wv;
        acc[2] += xa.z * wv; acc[3] += xa.w * wv;
        acc[4] += xb.x * wv; acc[5] += xb.y * wv;
        acc[6] += xb.z * wv; acc[7] += xb.w * wv;
    }
    #pragma unroll
    for (int i = 0; i < 8; ++i) {
        int r = m0 + ty * 8 + i;
        if (r < N_NODES) h2p[(size_t)r * H2P + tx] = __float2half(acc[i]);
    }
}

// ---------------------------------------------------------------------------
// agg2: per-node wave CSR gather on padded h2p rows (8 uint4 = 128B),
// 8 edges x 8 chunks, depth 2 (16 edges in flight) + srcw prefetch.
// fused +b2 + log_softmax (40 classes), f32 out.
// ---------------------------------------------------------------------------
__global__ __launch_bounds__(256) void agg2_kernel(const __half* __restrict__ h2p,
                                                   const int2* __restrict__ srcw,
                                                   const int* __restrict__ rowptr,
                                                   const float* __restrict__ b2,
                                                   float* __restrict__ out) {
    int lane = threadIdx.x & 63;
    int node = blockIdx.x * 4 + (threadIdx.x >> 6);
    if (node >= N_NODES) return;
    int beg = rowptr[node], end = rowptr[node + 1];
    int eo = lane >> 3, fo = lane & 7;           // 8 edges x 8 chunks(8 halfs)
    float4 a0 = {0.f, 0.f, 0.f, 0.f}, a1 = {0.f, 0.f, 0.f, 0.f};
    const uint4* hp = (const uint4*)h2p;         // row = 8 x uint4
    int idx0 = beg + lane;
    int2 sw = srcw[idx0 < end ? idx0 : end - 1];
    for (int base = beg; base < end; base += 64) {
        int cnt = end - base; if (cnt > 64) cnt = 64;
        int nidx = base + 64 + lane;
        int2 swn = srcw[nidx < end ? nidx : end - 1];
        for (int j = 0; j < cnt; j += 16) {
            int s[2]; float w[2];
            #pragma unroll
            for (int u = 0; u < 2; ++u) {
                int jj = j + u * 8 + eo;
                s[u] = __shfl(sw.x, jj);
                w[u] = __int_as_float(__shfl(sw.y, jj));
                if (jj >= cnt) w[u] = 0.f;
            }
            uint4 hv[2];
            #pragma unroll
            for (int u = 0; u < 2; ++u) hv[u] = hp[(size_t)s[u] * 8 + fo];
            #pragma unroll
            for (int u = 0; u < 2; ++u) {
                const __half2* p = (const __half2*)&hv[u];
                float2 f;
                f = __half22float2(p[0]); a0.x += w[u] * f.x; a0.y += w[u] * f.y;
                f = __half22float2(p[1]); a0.z += w[u] * f.x; a0.w += w[u] * f.y;
                f = __half22float2(p[2]); a1.x += w[u] * f.x; a1.y += w[u] * f.y;
                f = __half22float2(p[3]); a1.z += w[u] * f.x; a1.w += w[u] * f.y;
            }
        }
        sw = swn;
    }
    #pragma unroll
    for (int off = 8; off < 64; off <<= 1) {
        a0.x += __shfl_xor(a0.x, off); a0.y += __shfl_xor(a0.y, off);
        a0.z += __shfl_xor(a0.z, off); a0.w += __shfl_xor(a0.w, off);
        a1.x += __shfl_xor(a1.x, off); a1.y += __shfl_xor(a1.y, off);
        a1.z += __shfl_xor(a1.z, off); a1.w += __shfl_xor(a1.w, off);
    }
    // lanes 0..7 hold chunk fo (feats fo*8..fo*8+7); fo<5 are real classes
    float v[8];
    bool act = (lane < 8) && (fo < 5);
    #pragma unroll
    for (int t = 0; t < 8; ++t) v[t] = -INFINITY;
    if (act) {
        float4 bb0 = *(const float4*)&b2[fo * 8];
        float4 bb1 = *(const float4*)&b2[fo * 8 + 4];
        v[0] = a0.x + bb0.x; v[1] = a0.y + bb0.y;
        v[2] = a0.z + bb0.z; v[3] = a0.w + bb0.w;
        v[4] = a1.x + bb1.x; v[5] = a1.y + bb1.y;
        v[6] = a1.z + bb1.z; v[7] = a1.w + bb1.w;
    }
    float m = v[0];
    #pragma unroll
    for (int t = 1; t < 8; ++t) m = fmaxf(m, v[t]);
    #pragma unroll
    for (int off = 1; off < 8; off <<= 1) m = fmaxf(m, __shfl_xor(m, off));
    float ex = 0.f;
    if (act) {
        #pragma unroll
        for (int t = 0; t < 8; ++t) ex += expf(v[t] - m);
    }
    #pragma unroll
    for (int off = 1; off < 8; off <<= 1) ex += __shfl_xor(ex, off);
    float ls = logf(ex);
    if (act) {
        float4 o0 = { v[0]-m-ls, v[1]-m-ls, v[2]-m-ls, v[3]-m-ls };
        float4 o1 = { v[4]-m-ls, v[5]-m-ls, v[6]-m-ls, v[7]-m-ls };
        *(float4*)&out[(size_t)node * C_OUT + fo * 8] = o0;
        *(float4*)&out[(size_t)node * C_OUT + fo * 8 + 4] = o1;
    }
}

// ---------------------------------------------------------------------------

extern "C" void kernel_launch(void* const* d_in, const int* in_sizes, int n_in,
                              void* d_out, int out_size, void* d_ws, size_t ws_size,
                              hipStream_t stream) {
    const float* x  = (const float*)d_in[0];
    const int*   ei = (const int*)d_in[1];      // [2,E]: row0=src, row1=dst
    const float* ew = (const float*)d_in[2];
    const float* W1 = (const float*)d_in[3];
    const float* b1 = (const float*)d_in[4];
    const float* W2 = (const float*)d_in[5];
    const float* b2 = (const float*)d_in[6];
    float* out = (float*)d_out;

    char* ws = (char*)d_ws;
    size_t off = 0;
    auto alloc = [&](size_t bytes) -> void* {
        void* p = ws + off;
        off += (bytes + 255) & ~(size_t)255;
        return p;
    };
    __half* h      = (__half*)alloc((size_t)N_NODES * HIDF * 2);     // 25.6 MB
    __half* hact   = (__half*)alloc((size_t)N_NODES * HIDF * 2);     // 25.6 MB
    __half* h2p    = (__half*)alloc((size_t)N_NODES * H2P * 2);      // 12.8 MB
    short*  w1t    = (short*)alloc((size_t)HIDF * F_INF * 2);        // 64 KB
    int*    rowptr = (int*)alloc((size_t)(N_NODES + 1) * 4);
    int2*   srcw   = (int2*)alloc((size_t)E_EDGES * 8);              // 25.6 MB
    int2*   rec    = (int2*)alloc((size_t)NSEG * NB * CAPX * 8);     // 32 MB
    int*    cnt    = (int*)alloc((size_t)NSEG * NB * 4);             // 12.5 KB
    int*    ocnt   = (int*)alloc(256);
    int2*   osw    = (int2*)alloc((size_t)OCAP * 8);                 // 2 MB
    int*    odst   = (int*)alloc((size_t)OCAP * 4);                  // 1 MB

    hipMemsetAsync(cnt, 0, (size_t)NSEG * NB * 4, stream);
    hipMemsetAsync(ocnt, 0, 4, stream);

    scat_w1t_kernel<<<SCAT_BLOCKS + W1T_BLOCKS, 256, 0, stream>>>(
        ei, ew, cnt, rec, ocnt, osw, odst, W1, w1t);
    csr_gemm1_kernel<<<NB + GEMM1_BLOCKS, 256, 0, stream>>>(
        cnt, rec, ocnt, osw, odst, rowptr, srcw, x, w1t, h);
    agg1_kernel<<<(N_NODES + 3) / 4, 256, 0, stream>>>(h, srcw, rowptr, b1, hact);
    gemm2_kernel<<<(N_NODES + 63) / 64, 320, 0, stream>>>(hact, W2, h2p);
    agg2_kernel<<<(N_NODES + 3) / 4, 256, 0, stream>>>(h2p, srcw, rowptr, b2, out);
}